// Round 2
// baseline (820.718 us; speedup 1.0000x reference)
//
#include <hip/hip_runtime.h>

// MLA projection: T=4096, H=7168, N_HEADS=128, QK_NOPE=128, QK_ROPE=64, KV_RANK=512
// out row = [q (128*192=24576) | ckv (512) | k_rope (64)] = 25152 fp32

typedef __attribute__((ext_vector_type(8))) __bf16 bf16x8;
typedef __attribute__((ext_vector_type(4))) float f32x4;

#define OUT_LD 25152

__device__ __forceinline__ unsigned short f2bf(float f) {
  union { float f; unsigned u; } v; v.f = f;
  unsigned r = v.u + 0x7FFFu + ((v.u >> 16) & 1u);  // RNE
  return (unsigned short)(r >> 16);
}

__device__ __forceinline__ void gload16(const void* g, void* l) {
  __builtin_amdgcn_global_load_lds(
      (__attribute__((address_space(1))) void*)(void*)g,
      (__attribute__((address_space(3))) void*)l, 16, 0, 0);
}

// ---- fp32 -> bf16 straight conversion (token_x), 4 elems/thread ----
__global__ void cvt_bf16(const float* __restrict__ in, unsigned short* __restrict__ out) {
  size_t i = (size_t)blockIdx.x * 256 + threadIdx.x;
  float4 f = ((const float4*)in)[i];
  ushort4 o;
  o.x = f2bf(f.x); o.y = f2bf(f.y); o.z = f2bf(f.z); o.w = f2bf(f.w);
  ((ushort4*)out)[i] = o;
}

// ---- fp32 (K x N) -> bf16 (Npad x K) transpose+convert, zero pad rows >= N ----
__global__ void transpose_cvt(const float* __restrict__ in, unsigned short* __restrict__ out,
                              int K, int N, int Npad) {
  __shared__ float tile[32][33];
  int k0 = blockIdx.x * 32, n0 = blockIdx.y * 32;
  int tx = threadIdx.x, ty = threadIdx.y;  // 32 x 8
#pragma unroll
  for (int i = 0; i < 4; ++i) {
    int k = k0 + ty + i * 8;
    int n = n0 + tx;
    tile[ty + i * 8][tx] = (n < N) ? in[(size_t)k * N + n] : 0.f;
  }
  __syncthreads();
#pragma unroll
  for (int i = 0; i < 4; ++i) {
    int n = n0 + ty + i * 8;
    int k = k0 + tx;
    if (n < Npad) out[(size_t)n * K + k] = f2bf(tile[tx][ty + i * 8]);
  }
}

// ---- 128x128 bf16 GEMM (m97 structure): A (M,K) k-contig, B (N,K) k-contig, C fp32 ----
__global__ __launch_bounds__(256, 2) void gemm128(
    const unsigned short* __restrict__ A, const unsigned short* __restrict__ B,
    float* __restrict__ C, int K, int ldc, int Nvalid) {
  __shared__ __attribute__((aligned(128))) unsigned short As[128 * 32];
  __shared__ __attribute__((aligned(128))) unsigned short Bs[128 * 32];
  const int tid = threadIdx.x;
  const int lane = tid & 63;
  const int wid = tid >> 6;
  const int wr = wid >> 1, wc = wid & 1;
  const int bm = blockIdx.y, bn = blockIdx.x;
  const size_t abase = (size_t)bm * 128 * K;
  const size_t bbase = (size_t)bn * 128 * K;

  f32x4 acc[4][4];
  const f32x4 zero4 = {0.f, 0.f, 0.f, 0.f};
#pragma unroll
  for (int m = 0; m < 4; ++m)
#pragma unroll
    for (int n = 0; n < 4; ++n) acc[m][n] = zero4;

  const int r0 = tid >> 2;       // 0..63
  const int c0 = (tid & 3) * 8;  // k-chunk offset (shorts)

  for (int k0 = 0; k0 < K; k0 += 32) {
    gload16(A + abase + (size_t)r0 * K + k0 + c0, As + tid * 8);
    gload16(A + abase + (size_t)(r0 + 64) * K + k0 + c0, As + (256 + tid) * 8);
    gload16(B + bbase + (size_t)r0 * K + k0 + c0, Bs + tid * 8);
    gload16(B + bbase + (size_t)(r0 + 64) * K + k0 + c0, Bs + (256 + tid) * 8);
    __syncthreads();  // drains vmcnt -> tiles staged
    bf16x8 af[4], bfr[4];
#pragma unroll
    for (int m = 0; m < 4; ++m)
      af[m] = *(const bf16x8*)(As + (wr * 64 + m * 16 + (lane & 15)) * 32 + (lane >> 4) * 8);
#pragma unroll
    for (int n = 0; n < 4; ++n)
      bfr[n] = *(const bf16x8*)(Bs + (wc * 64 + n * 16 + (lane & 15)) * 32 + (lane >> 4) * 8);
#pragma unroll
    for (int m = 0; m < 4; ++m)
#pragma unroll
      for (int n = 0; n < 4; ++n)
        acc[m][n] = __builtin_amdgcn_mfma_f32_16x16x32_bf16(af[m], bfr[n], acc[m][n], 0, 0, 0);
    __syncthreads();  // before next stage overwrites LDS
  }

  const int crow0 = bm * 128 + wr * 64 + ((lane >> 4) << 2);
  const int ccol0 = bn * 128 + wc * 64 + (lane & 15);
#pragma unroll
  for (int m = 0; m < 4; ++m) {
#pragma unroll
    for (int n = 0; n < 4; ++n) {
      int col = ccol0 + n * 16;
      if (col < Nvalid) {
#pragma unroll
        for (int r = 0; r < 4; ++r) {
          int row = crow0 + m * 16 + r;
          C[(size_t)row * ldc + col] = acc[m][n][r];
        }
      }
    }
  }
}

// ---- rmsnorm over cq rows (1536), raw stride 2176, out bf16 ----
__global__ void rmsnorm_cq(const float* __restrict__ raw, const float* __restrict__ gamma,
                           unsigned short* __restrict__ out) {
  __shared__ float red[4];
  int t = blockIdx.x, tid = threadIdx.x;
  const float* r = raw + (size_t)t * 2176;
  float v[6];
  float ss = 0.f;
#pragma unroll
  for (int i = 0; i < 6; ++i) {
    v[i] = r[tid + i * 256];
    ss += v[i] * v[i];
  }
#pragma unroll
  for (int o = 32; o > 0; o >>= 1) ss += __shfl_xor(ss, o, 64);
  if ((tid & 63) == 0) red[tid >> 6] = ss;
  __syncthreads();
  ss = red[0] + red[1] + red[2] + red[3];
  float sc = rsqrtf(ss * (1.f / 1536.f) + 1e-6f);
#pragma unroll
  for (int i = 0; i < 6; ++i)
    out[(size_t)t * 1536 + tid + i * 256] = f2bf(v[i] * sc * gamma[tid + i * 256]);
}

// ---- kv epilogue: rmsnorm(kv[:512]) + rope(kv[512:576]) -> out cols 24576..25152 ----
__global__ void kv_epi(const float* __restrict__ raw, const float* __restrict__ gamma,
                       const float* __restrict__ cs, const float* __restrict__ sn,
                       float* __restrict__ out) {
  __shared__ float red[4];
  int t = blockIdx.x, tid = threadIdx.x;
  const float* r = raw + (size_t)t * 2176 + 1536;
  float v0 = r[tid], v1 = r[tid + 256];
  float ss = v0 * v0 + v1 * v1;
#pragma unroll
  for (int o = 32; o > 0; o >>= 1) ss += __shfl_xor(ss, o, 64);
  if ((tid & 63) == 0) red[tid >> 6] = ss;
  __syncthreads();
  ss = red[0] + red[1] + red[2] + red[3];
  float sc = rsqrtf(ss * (1.f / 512.f) + 1e-6f);
  float* orow = out + (size_t)t * OUT_LD + 24576;
  orow[tid] = v0 * sc * gamma[tid];
  orow[tid + 256] = v1 * sc * gamma[tid + 256];
  if (tid < 32) {
    float a = r[512 + tid], b = r[544 + tid];
    orow[512 + tid] = a * cs[t * 64 + tid] - b * sn[t * 64 + tid];
    orow[544 + tid] = b * cs[t * 64 + 32 + tid] + a * sn[t * 64 + 32 + tid];
  }
}

// ---- in-place rope on q_rope slices of out ----
__global__ void rope_q(float* __restrict__ out, const float* __restrict__ cs,
                       const float* __restrict__ sn) {
  int idx = blockIdx.x * 256 + threadIdx.x;  // T*128*32 = 16777216
  int i = idx & 31;
  int h = (idx >> 5) & 127;
  int t = idx >> 12;
  float* p = out + (size_t)t * OUT_LD + h * 192 + 128;
  float a = p[i], b = p[32 + i];
  float c1 = cs[t * 64 + i], s1 = sn[t * 64 + i];
  float c2 = cs[t * 64 + 32 + i], s2 = sn[t * 64 + 32 + i];
  p[i] = a * c1 - b * s1;
  p[32 + i] = b * c2 + a * s2;
}

extern "C" void kernel_launch(void* const* d_in, const int* in_sizes, int n_in,
                              void* d_out, int out_size, void* d_ws, size_t ws_size,
                              hipStream_t stream) {
  const float* token_x = (const float*)d_in[0];   // 4096 x 7168
  const float* wq_a = (const float*)d_in[1];      // 7168 x 1536
  const float* wq_b = (const float*)d_in[2];      // 1536 x 24576
  const float* wkv = (const float*)d_in[3];       // 7168 x 576
  const float* rope_cos = (const float*)d_in[4];  // 4096 x 64
  const float* rope_sin = (const float*)d_in[5];
  const float* gamma_cq = (const float*)d_in[6];   // 1536
  const float* gamma_ckv = (const float*)d_in[7];  // 512
  float* out = (float*)d_out;                      // 4096 x 25152

  char* ws = (char*)d_ws;
  unsigned short* txb = (unsigned short*)ws;                          // 4096x7168 bf16 (58,720,256 B)
  unsigned short* wqbT = (unsigned short*)(ws + 58720256);            // 24576x1536 bf16 (75,497,472 B)
  unsigned short* Bc = (unsigned short*)(ws + 134217728);             // 2176x7168 bf16 (31,195,136 B)
  float* raw = (float*)(ws + 165412864);                              // 4096x2176 f32 (35,651,584 B)
  unsigned short* cqb = (unsigned short*)(ws + 201064448);            // 4096x1536 bf16 (12,582,912 B)
  // total ws: 213,647,360 B

  // 1) conversions
  cvt_bf16<<<28672, 256, 0, stream>>>(token_x, txb);
  transpose_cvt<<<dim3(7168 / 32, 1536 / 32), dim3(32, 8), 0, stream>>>(wq_a, Bc, 7168, 1536, 1536);
  transpose_cvt<<<dim3(7168 / 32, 640 / 32), dim3(32, 8), 0, stream>>>(
      wkv, Bc + (size_t)1536 * 7168, 7168, 576, 640);
  transpose_cvt<<<dim3(1536 / 32, 24576 / 32), dim3(32, 8), 0, stream>>>(wq_b, wqbT, 1536, 24576, 24576);

  // 2) fused GEMM1+GEMM3: raw = token_x @ [wq_a | wkv | 0pad]  (4096 x 2176, K=7168)
  gemm128<<<dim3(17, 32), 256, 0, stream>>>(txb, Bc, raw, 7168, 2176, 2176);

  // 3) epilogues of stage 1
  rmsnorm_cq<<<4096, 256, 0, stream>>>(raw, gamma_cq, cqb);
  kv_epi<<<4096, 256, 0, stream>>>(raw, gamma_ckv, rope_cos, rope_sin, out);

  // 4) GEMM2: q = cq @ wq_b -> out cols [0, 24576), K=1536
  gemm128<<<dim3(192, 32), 256, 0, stream>>>(cqb, wqbT, out, 1536, OUT_LD, 24576);

  // 5) in-place rope on q_rope columns
  rope_q<<<65536, 256, 0, stream>>>(out, rope_cos, rope_sin);
}

// Round 3
// 799.539 us; speedup vs baseline: 1.0265x; 1.0265x over previous
//
#include <hip/hip_runtime.h>

// MLA projection: T=4096, H=7168, N_HEADS=128, QK_NOPE=128, QK_ROPE=64, KV_RANK=512
// out row = [q (128*192=24576) | ckv (512) | k_rope (64)] = 25152 fp32

typedef __attribute__((ext_vector_type(8))) __bf16 bf16x8;
typedef __attribute__((ext_vector_type(4))) float f32x4;

#define OUT_LD 25152

__device__ __forceinline__ unsigned short f2bf(float f) {
  union { float f; unsigned u; } v; v.f = f;
  unsigned r = v.u + 0x7FFFu + ((v.u >> 16) & 1u);  // RNE
  return (unsigned short)(r >> 16);
}

__device__ __forceinline__ void gload16(const void* g, void* l) {
  __builtin_amdgcn_global_load_lds(
      (__attribute__((address_space(1))) void*)(void*)g,
      (__attribute__((address_space(3))) void*)l, 16, 0, 0);
}

// ---- fp32 -> bf16 straight conversion (token_x), 4 elems/thread ----
__global__ void cvt_bf16(const float* __restrict__ in, unsigned short* __restrict__ out) {
  size_t i = (size_t)blockIdx.x * 256 + threadIdx.x;
  float4 f = ((const float4*)in)[i];
  ushort4 o;
  o.x = f2bf(f.x); o.y = f2bf(f.y); o.z = f2bf(f.z); o.w = f2bf(f.w);
  ((ushort4*)out)[i] = o;
}

// ---- fp32 (K x N) -> bf16 (Npad x K) transpose+convert, zero pad rows >= N ----
__global__ void transpose_cvt(const float* __restrict__ in, unsigned short* __restrict__ out,
                              int K, int N, int Npad) {
  __shared__ float tile[32][33];
  int k0 = blockIdx.x * 32, n0 = blockIdx.y * 32;
  int tx = threadIdx.x, ty = threadIdx.y;  // 32 x 8
#pragma unroll
  for (int i = 0; i < 4; ++i) {
    int k = k0 + ty + i * 8;
    int n = n0 + tx;
    tile[ty + i * 8][tx] = (n < N) ? in[(size_t)k * N + n] : 0.f;
  }
  __syncthreads();
#pragma unroll
  for (int i = 0; i < 4; ++i) {
    int n = n0 + ty + i * 8;
    int k = k0 + tx;
    if (n < Npad) out[(size_t)n * K + k] = f2bf(tile[tx][ty + i * 8]);
  }
}

// ======================================================================
// 256x256 8-phase GEMM (T1 XCD-swizzle + T2 LDS-swizzle + T3/T4 counted
// vmcnt pipeline + T5 setprio), A (M,K) k-contig, B (N,K) k-contig, C fp32.
// 512 threads = 8 waves (2 M x 4 N). BK=64. LDS 128 KiB (2 dbuf x (A 32K + B 32K)).
// Optional fused q-RoPE epilogue (rope!=0).
// ======================================================================
__global__ __launch_bounds__(512, 2) void gemm256(
    const unsigned short* __restrict__ A, const unsigned short* __restrict__ B,
    float* __restrict__ C, int K, int ldc, int Mtiles,
    const float* __restrict__ cs, const float* __restrict__ sn, int rope) {
  __shared__ __attribute__((aligned(128))) char lds[131072];
  const int tid = threadIdx.x;
  const int lane = tid & 63;
  const int wr = (tid >> 6) >> 2;  // 0..1
  const int wc = (tid >> 6) & 3;   // 0..3
  const int NT = K >> 6;

  // T1: XCD-aware block swizzle (grid size % 8 == 0 guaranteed by launch)
  const int nwg = gridDim.x;
  const int per = nwg >> 3;
  const int bid = blockIdx.x;
  const int swz = (bid & 7) * per + (bid >> 3);
  const int bm = swz % Mtiles, bn = swz / Mtiles;

  // staging geometry: thread covers 16 B at linear unit byte tid*16;
  // source column pre-swizzled so that read-side XOR sees logical layout (rule #21)
  const int strow = tid >> 3;                                       // row within 64-row unit
  const int stcolb = ((tid & 7) << 4) ^ (((tid >> 5) & 1) << 5);    // byte col 0..127, pre-swizzled
  const size_t abase = (size_t)(bm * 256) * K;
  const size_t bbase = (size_t)(bn * 256) * K;

  f32x4 acc[2][2][4][2];
  const f32x4 z4 = {0.f, 0.f, 0.f, 0.f};
#pragma unroll
  for (int a = 0; a < 2; ++a)
#pragma unroll
    for (int b = 0; b < 2; ++b)
#pragma unroll
      for (int c = 0; c < 4; ++c)
#pragma unroll
        for (int d = 0; d < 2; ++d) acc[a][b][c][d] = z4;

// A LDS: region buf*65536 + 0,     rows 0..255 natural (row = m), 128 B/row
// B LDS: region buf*65536 + 32768, rows permuted: ldsrow(n) = ((n>>5)&1)*128 + ((n>>6)&3)*32 + (n&31)
#define STAGE_A(kt, bsel, u)                                                        \
  do {                                                                              \
    int row_ = (u) * 64 + strow;                                                    \
    gload16((const char*)(A + abase + (size_t)row_ * K + (size_t)(kt) * 64) + stcolb, \
            lds + (bsel) * 65536 + (u) * 8192 + tid * 16);                          \
  } while (0)
#define STAGE_B(kt, bsel, u)                                                        \
  do {                                                                              \
    int lrow_ = (u) * 64 + strow;                                                   \
    int n_ = ((lrow_ >> 5) & 3) * 64 + ((lrow_ >> 7) & 1) * 32 + (lrow_ & 31);      \
    gload16((const char*)(B + bbase + (size_t)n_ * K + (size_t)(kt) * 64) + stcolb, \
            lds + (bsel) * 65536 + 32768 + (u) * 8192 + tid * 16);                  \
  } while (0)

  // ---- prologue: tile0 full (8 units) + tile1's ph3/ph4-class units (4) ----
  STAGE_A(0, 0, 0); STAGE_A(0, 0, 1); STAGE_A(0, 0, 2); STAGE_A(0, 0, 3);
  STAGE_B(0, 0, 0); STAGE_B(0, 0, 1); STAGE_B(0, 0, 2); STAGE_B(0, 0, 3);
  if (NT > 1) {
    STAGE_A(1, 1, 0); STAGE_A(1, 1, 1);
    STAGE_B(1, 1, 2); STAGE_B(1, 1, 3);
    asm volatile("s_waitcnt vmcnt(4)" ::: "memory");
  } else {
    asm volatile("s_waitcnt vmcnt(0)" ::: "memory");
  }
  __builtin_amdgcn_s_barrier();
  __builtin_amdgcn_sched_barrier(0);

#define PHASE(QM, QN, STAGES)                                                        \
  do {                                                                               \
    const char* Lb_ = lds + buf * 65536;                                             \
    bf16x8 af_[4][2], bb_[2][2];                                                     \
    _Pragma("unroll") for (int mf = 0; mf < 4; ++mf)                                 \
        _Pragma("unroll") for (int ks = 0; ks < 2; ++ks) {                           \
      int row_ = (QM) * 128 + wr * 64 + mf * 16 + (lane & 15);                       \
      int tb_ = row_ * 128 + ks * 64 + ((lane >> 4) << 4);                           \
      af_[mf][ks] = *(const bf16x8*)(Lb_ + (tb_ ^ (((row_ >> 2) & 1) << 5)));        \
    }                                                                                \
    _Pragma("unroll") for (int nf = 0; nf < 2; ++nf)                                 \
        _Pragma("unroll") for (int ks = 0; ks < 2; ++ks) {                           \
      int c_ = wc * 64 + (QN) * 32 + nf * 16 + (lane & 15);                          \
      int rr_ = ((c_ >> 5) & 1) * 128 + ((c_ >> 6) & 3) * 32 + (c_ & 31);            \
      int tb_ = rr_ * 128 + ks * 64 + ((lane >> 4) << 4);                            \
      bb_[nf][ks] = *(const bf16x8*)(Lb_ + 32768 + (tb_ ^ (((rr_ >> 2) & 1) << 5))); \
    }                                                                                \
    STAGES;                                                                          \
    __builtin_amdgcn_s_barrier();                                                    \
    asm volatile("s_waitcnt lgkmcnt(0)" ::: "memory");                               \
    __builtin_amdgcn_sched_barrier(0);                                               \
    __builtin_amdgcn_s_setprio(1);                                                   \
    _Pragma("unroll") for (int mf = 0; mf < 4; ++mf)                                 \
        _Pragma("unroll") for (int nf = 0; nf < 2; ++nf)                             \
            _Pragma("unroll") for (int ks = 0; ks < 2; ++ks)                         \
                acc[QM][QN][mf][nf] = __builtin_amdgcn_mfma_f32_16x16x32_bf16(       \
                    af_[mf][ks], bb_[nf][ks], acc[QM][QN][mf][nf], 0, 0, 0);         \
    __builtin_amdgcn_s_setprio(0);                                                   \
  } while (0)

  for (int t = 0; t < NT; ++t) {
    const int buf = t & 1;
    const int pb = buf ^ 1;
    // ph1 (0,0): stage A(t+1) upper half -> other buffer (free since t-1 done)
    PHASE(0, 0, { if (t + 1 < NT) { STAGE_A(t + 1, pb, 2); STAGE_A(t + 1, pb, 3); } });
    __builtin_amdgcn_s_barrier();
    // ph2 (0,1): stage B(t+1) lower half -> other buffer
    PHASE(0, 1, { if (t + 1 < NT) { STAGE_B(t + 1, pb, 0); STAGE_B(t + 1, pb, 1); } });
    __builtin_amdgcn_s_barrier();
    // ph3 (1,1): stage A(t+2) lower half -> THIS buffer (A-lower last read ph2; barrier-safe)
    PHASE(1, 1, { if (t + 2 < NT) { STAGE_A(t + 2, buf, 0); STAGE_A(t + 2, buf, 1); } });
    __builtin_amdgcn_s_barrier();
    // ph4 (1,0): stage B(t+2) upper half -> THIS buffer (B-upper last read ph3)
    PHASE(1, 0, { if (t + 2 < NT) { STAGE_B(t + 2, buf, 2); STAGE_B(t + 2, buf, 3); } });
    // boundary: counted vmcnt (T4) — leave t+2's 4 loads in flight; then barrier
    if (t + 2 < NT) {
      asm volatile("s_waitcnt vmcnt(4)" ::: "memory");
    } else {
      asm volatile("s_waitcnt vmcnt(0)" ::: "memory");
    }
    __builtin_amdgcn_s_barrier();
    __builtin_amdgcn_sched_barrier(0);
  }

  // ---- epilogue: C write, optional fused RoPE on 64-col rope strips ----
  const int colbase = bn * 256 + wc * 64;
  const int rbase = bm * 256 + wr * 64 + ((lane >> 4) << 2);
  const bool isrope = rope && ((colbase % 192) == 128);
  if (isrope) {
#pragma unroll
    for (int qm = 0; qm < 2; ++qm)
#pragma unroll
      for (int mf = 0; mf < 4; ++mf)
#pragma unroll
        for (int nf = 0; nf < 2; ++nf) {
          int i_ = nf * 16 + (lane & 15);
#pragma unroll
          for (int r = 0; r < 4; ++r) {
            int trow = rbase + qm * 128 + mf * 16 + r;
            float c1 = cs[trow * 64 + i_], s1 = sn[trow * 64 + i_];
            float c2 = cs[trow * 64 + 32 + i_], s2 = sn[trow * 64 + 32 + i_];
            float a = acc[qm][0][mf][nf][r], b = acc[qm][1][mf][nf][r];
            C[(size_t)trow * ldc + colbase + i_] = a * c1 - b * s1;
            C[(size_t)trow * ldc + colbase + 32 + i_] = b * c2 + a * s2;
          }
        }
  } else {
#pragma unroll
    for (int qm = 0; qm < 2; ++qm)
#pragma unroll
      for (int qn = 0; qn < 2; ++qn)
#pragma unroll
        for (int mf = 0; mf < 4; ++mf)
#pragma unroll
          for (int nf = 0; nf < 2; ++nf)
#pragma unroll
            for (int r = 0; r < 4; ++r) {
              int trow = rbase + qm * 128 + mf * 16 + r;
              C[(size_t)trow * ldc + colbase + qn * 32 + nf * 16 + (lane & 15)] =
                  acc[qm][qn][mf][nf][r];
            }
  }
#undef PHASE
#undef STAGE_A
#undef STAGE_B
}

// ---- 128x128 bf16 GEMM (m97 structure) for GEMM1+3: A (M,K), B (N,K), C fp32 ----
__global__ __launch_bounds__(256, 2) void gemm128(
    const unsigned short* __restrict__ A, const unsigned short* __restrict__ B,
    float* __restrict__ C, int K, int ldc, int Nvalid) {
  __shared__ __attribute__((aligned(128))) unsigned short As[128 * 32];
  __shared__ __attribute__((aligned(128))) unsigned short Bs[128 * 32];
  const int tid = threadIdx.x;
  const int lane = tid & 63;
  const int wid = tid >> 6;
  const int wr = wid >> 1, wc = wid & 1;
  const int bm = blockIdx.y, bn = blockIdx.x;
  const size_t abase = (size_t)bm * 128 * K;
  const size_t bbase = (size_t)bn * 128 * K;

  f32x4 acc[4][4];
  const f32x4 zero4 = {0.f, 0.f, 0.f, 0.f};
#pragma unroll
  for (int m = 0; m < 4; ++m)
#pragma unroll
    for (int n = 0; n < 4; ++n) acc[m][n] = zero4;

  const int r0 = tid >> 2;
  const int c0 = (tid & 3) * 8;

  for (int k0 = 0; k0 < K; k0 += 32) {
    gload16(A + abase + (size_t)r0 * K + k0 + c0, As + tid * 8);
    gload16(A + abase + (size_t)(r0 + 64) * K + k0 + c0, As + (256 + tid) * 8);
    gload16(B + bbase + (size_t)r0 * K + k0 + c0, Bs + tid * 8);
    gload16(B + bbase + (size_t)(r0 + 64) * K + k0 + c0, Bs + (256 + tid) * 8);
    __syncthreads();
    bf16x8 af[4], bfr[4];
#pragma unroll
    for (int m = 0; m < 4; ++m)
      af[m] = *(const bf16x8*)(As + (wr * 64 + m * 16 + (lane & 15)) * 32 + (lane >> 4) * 8);
#pragma unroll
    for (int n = 0; n < 4; ++n)
      bfr[n] = *(const bf16x8*)(Bs + (wc * 64 + n * 16 + (lane & 15)) * 32 + (lane >> 4) * 8);
#pragma unroll
    for (int m = 0; m < 4; ++m)
#pragma unroll
      for (int n = 0; n < 4; ++n)
        acc[m][n] = __builtin_amdgcn_mfma_f32_16x16x32_bf16(af[m], bfr[n], acc[m][n], 0, 0, 0);
    __syncthreads();
  }

  const int crow0 = bm * 128 + wr * 64 + ((lane >> 4) << 2);
  const int ccol0 = bn * 128 + wc * 64 + (lane & 15);
#pragma unroll
  for (int m = 0; m < 4; ++m) {
#pragma unroll
    for (int n = 0; n < 4; ++n) {
      int col = ccol0 + n * 16;
      if (col < Nvalid) {
#pragma unroll
        for (int r = 0; r < 4; ++r) {
          int row = crow0 + m * 16 + r;
          C[(size_t)row * ldc + col] = acc[m][n][r];
        }
      }
    }
  }
}

// ---- rmsnorm over cq rows (1536), raw stride 2176, out bf16 ----
__global__ void rmsnorm_cq(const float* __restrict__ raw, const float* __restrict__ gamma,
                           unsigned short* __restrict__ out) {
  __shared__ float red[4];
  int t = blockIdx.x, tid = threadIdx.x;
  const float* r = raw + (size_t)t * 2176;
  float v[6];
  float ss = 0.f;
#pragma unroll
  for (int i = 0; i < 6; ++i) {
    v[i] = r[tid + i * 256];
    ss += v[i] * v[i];
  }
#pragma unroll
  for (int o = 32; o > 0; o >>= 1) ss += __shfl_xor(ss, o, 64);
  if ((tid & 63) == 0) red[tid >> 6] = ss;
  __syncthreads();
  ss = red[0] + red[1] + red[2] + red[3];
  float sc = rsqrtf(ss * (1.f / 1536.f) + 1e-6f);
#pragma unroll
  for (int i = 0; i < 6; ++i)
    out[(size_t)t * 1536 + tid + i * 256] = f2bf(v[i] * sc * gamma[tid + i * 256]);
}

// ---- kv epilogue: rmsnorm(kv[:512]) + rope(kv[512:576]) -> out cols 24576..25152 ----
__global__ void kv_epi(const float* __restrict__ raw, const float* __restrict__ gamma,
                       const float* __restrict__ cs, const float* __restrict__ sn,
                       float* __restrict__ out) {
  __shared__ float red[4];
  int t = blockIdx.x, tid = threadIdx.x;
  const float* r = raw + (size_t)t * 2176 + 1536;
  float v0 = r[tid], v1 = r[tid + 256];
  float ss = v0 * v0 + v1 * v1;
#pragma unroll
  for (int o = 32; o > 0; o >>= 1) ss += __shfl_xor(ss, o, 64);
  if ((tid & 63) == 0) red[tid >> 6] = ss;
  __syncthreads();
  ss = red[0] + red[1] + red[2] + red[3];
  float sc = rsqrtf(ss * (1.f / 512.f) + 1e-6f);
  float* orow = out + (size_t)t * OUT_LD + 24576;
  orow[tid] = v0 * sc * gamma[tid];
  orow[tid + 256] = v1 * sc * gamma[tid + 256];
  if (tid < 32) {
    float a = r[512 + tid], b = r[544 + tid];
    orow[512 + tid] = a * cs[t * 64 + tid] - b * sn[t * 64 + tid];
    orow[544 + tid] = b * cs[t * 64 + 32 + tid] + a * sn[t * 64 + 32 + tid];
  }
}

extern "C" void kernel_launch(void* const* d_in, const int* in_sizes, int n_in,
                              void* d_out, int out_size, void* d_ws, size_t ws_size,
                              hipStream_t stream) {
  const float* token_x = (const float*)d_in[0];   // 4096 x 7168
  const float* wq_a = (const float*)d_in[1];      // 7168 x 1536
  const float* wq_b = (const float*)d_in[2];      // 1536 x 24576
  const float* wkv = (const float*)d_in[3];       // 7168 x 576
  const float* rope_cos = (const float*)d_in[4];  // 4096 x 64
  const float* rope_sin = (const float*)d_in[5];
  const float* gamma_cq = (const float*)d_in[6];   // 1536
  const float* gamma_ckv = (const float*)d_in[7];  // 512
  float* out = (float*)d_out;                      // 4096 x 25152

  char* ws = (char*)d_ws;
  unsigned short* txb = (unsigned short*)ws;                          // 4096x7168 bf16
  unsigned short* wqbT = (unsigned short*)(ws + 58720256);            // 24576x1536 bf16
  unsigned short* Bc = (unsigned short*)(ws + 134217728);             // 2176x7168 bf16
  float* raw = (float*)(ws + 165412864);                              // 4096x2176 f32
  unsigned short* cqb = (unsigned short*)(ws + 201064448);            // 4096x1536 bf16

  // 1) conversions
  cvt_bf16<<<28672, 256, 0, stream>>>(token_x, txb);
  transpose_cvt<<<dim3(7168 / 32, 1536 / 32), dim3(32, 8), 0, stream>>>(wq_a, Bc, 7168, 1536, 1536);
  transpose_cvt<<<dim3(7168 / 32, 640 / 32), dim3(32, 8), 0, stream>>>(
      wkv, Bc + (size_t)1536 * 7168, 7168, 576, 640);
  transpose_cvt<<<dim3(1536 / 32, 24576 / 32), dim3(32, 8), 0, stream>>>(wq_b, wqbT, 1536, 24576, 24576);

  // 2) fused GEMM1+GEMM3: raw = token_x @ [wq_a | wkv | 0pad]  (4096 x 2176, K=7168)
  gemm128<<<dim3(17, 32), 256, 0, stream>>>(txb, Bc, raw, 7168, 2176, 2176);

  // 3) epilogues of stage 1
  rmsnorm_cq<<<4096, 256, 0, stream>>>(raw, gamma_cq, cqb);
  kv_epi<<<4096, 256, 0, stream>>>(raw, gamma_ckv, rope_cos, rope_sin, out);

  // 4) GEMM2 (8-phase 256^2, fused rope): q = cq @ wq_b -> out cols [0, 24576), K=1536
  //    grid = 16 Mtiles * 96 Ntiles = 1536 (% 8 == 0 for XCD swizzle)
  gemm256<<<1536, 512, 0, stream>>>(cqb, wqbT, out, 1536, OUT_LD, 16, rope_cos, rope_sin, 1);
}

// Round 4
// 732.368 us; speedup vs baseline: 1.1206x; 1.0917x over previous
//
#include <hip/hip_runtime.h>

// MLA projection: T=4096, H=7168, N_HEADS=128, QK_NOPE=128, QK_ROPE=64, KV_RANK=512
// out row = [q (128*192=24576) | ckv (512) | k_rope (64)] = 25152 fp32

typedef __attribute__((ext_vector_type(8))) __bf16 bf16x8;
typedef __attribute__((ext_vector_type(4))) float f32x4;

#define OUT_LD 25152

__device__ __forceinline__ unsigned short f2bf(float f) {
  union { float f; unsigned u; } v; v.f = f;
  unsigned r = v.u + 0x7FFFu + ((v.u >> 16) & 1u);  // RNE
  return (unsigned short)(r >> 16);
}

__device__ __forceinline__ void gload16(const void* g, void* l) {
  __builtin_amdgcn_global_load_lds(
      (__attribute__((address_space(1))) void*)(void*)g,
      (__attribute__((address_space(3))) void*)l, 16, 0, 0);
}

// ---- fp32 -> bf16 straight conversion (token_x), 4 elems/thread ----
__global__ void cvt_bf16(const float* __restrict__ in, unsigned short* __restrict__ out) {
  size_t i = (size_t)blockIdx.x * 256 + threadIdx.x;
  float4 f = ((const float4*)in)[i];
  ushort4 o;
  o.x = f2bf(f.x); o.y = f2bf(f.y); o.z = f2bf(f.z); o.w = f2bf(f.w);
  ((ushort4*)out)[i] = o;
}

// ---- fp32 (K x N) -> bf16 (Npad x K) transpose+convert, zero pad rows >= N ----
__global__ void transpose_cvt(const float* __restrict__ in, unsigned short* __restrict__ out,
                              int K, int N, int Npad) {
  __shared__ float tile[32][33];
  int k0 = blockIdx.x * 32, n0 = blockIdx.y * 32;
  int tx = threadIdx.x, ty = threadIdx.y;  // 32 x 8
#pragma unroll
  for (int i = 0; i < 4; ++i) {
    int k = k0 + ty + i * 8;
    int n = n0 + tx;
    tile[ty + i * 8][tx] = (n < N) ? in[(size_t)k * N + n] : 0.f;
  }
  __syncthreads();
#pragma unroll
  for (int i = 0; i < 4; ++i) {
    int n = n0 + ty + i * 8;
    int k = k0 + tx;
    if (n < Npad) out[(size_t)n * K + k] = f2bf(tile[tx][ty + i * 8]);
  }
}

// ======================================================================
// 256x256 8-phase GEMM (T1 XCD-swizzle + T2 3-bit LDS XOR-swizzle + T3/T4
// counted vmcnt pipeline + T5 setprio). A (M,K) k-contig, B (N,K) k-contig.
// 512 threads = 8 waves (2 M x 4 N). BK=64. LDS 128 KiB (2 dbuf x (A 32K + B 32K)).
// LDS swizzle: byte-in-row ^= (ldsrow & 7) << 4  (granule spread across all
// 8 banks-groups; stage source pre-permuted with the same involution).
// Optional fused q-RoPE epilogue (rope!=0).
// ======================================================================
__global__ __launch_bounds__(512, 2) void gemm256(
    const unsigned short* __restrict__ A, const unsigned short* __restrict__ B,
    float* __restrict__ C, int K, int ldc, int Mtiles,
    const float* __restrict__ cs, const float* __restrict__ sn, int rope) {
  __shared__ __attribute__((aligned(128))) char lds[131072];
  const int tid = threadIdx.x;
  const int lane = tid & 63;
  const int wr = (tid >> 6) >> 2;  // 0..1
  const int wc = (tid >> 6) & 3;   // 0..3
  const int NT = K >> 6;

  // T1: XCD-aware block swizzle (grid size % 8 == 0 guaranteed by launch)
  const int nwg = gridDim.x;
  const int per = nwg >> 3;
  const int bid = blockIdx.x;
  const int swz = (bid & 7) * per + (bid >> 3);
  const int bm = swz % Mtiles, bn = swz / Mtiles;

  // staging geometry: thread covers 16 B at linear LDS byte tid*16;
  // ldsrow = tid>>3 (within 64-row unit), chunk = tid&7.
  // source column pre-swizzled: colbyte = (chunk ^ (ldsrow&7)) << 4  (rule #21)
  const int strow = tid >> 3;
  const int stcolb = (((tid & 7) ^ ((tid >> 3) & 7)) << 4);
  const size_t abase = (size_t)(bm * 256) * K;
  const size_t bbase = (size_t)(bn * 256) * K;

  f32x4 acc[2][2][4][2];
  const f32x4 z4 = {0.f, 0.f, 0.f, 0.f};
#pragma unroll
  for (int a = 0; a < 2; ++a)
#pragma unroll
    for (int b = 0; b < 2; ++b)
#pragma unroll
      for (int c = 0; c < 4; ++c)
#pragma unroll
        for (int d = 0; d < 2; ++d) acc[a][b][c][d] = z4;

// A LDS: region buf*65536 + 0,     rows 0..255 natural (row = m), 128 B/row
// B LDS: region buf*65536 + 32768, rows permuted: ldsrow(n) = ((n>>5)&1)*128 + ((n>>6)&3)*32 + (n&31)
#define STAGE_A(kt, bsel, u)                                                          \
  do {                                                                                \
    int row_ = (u) * 64 + strow;                                                      \
    gload16((const char*)(A + abase + (size_t)row_ * K + (size_t)(kt) * 64) + stcolb, \
            lds + (bsel) * 65536 + (u) * 8192 + tid * 16);                            \
  } while (0)
#define STAGE_B(kt, bsel, u)                                                          \
  do {                                                                                \
    int lrow_ = (u) * 64 + strow;                                                     \
    int n_ = ((lrow_ >> 5) & 3) * 64 + ((lrow_ >> 7) & 1) * 32 + (lrow_ & 31);        \
    gload16((const char*)(B + bbase + (size_t)n_ * K + (size_t)(kt) * 64) + stcolb,   \
            lds + (bsel) * 65536 + 32768 + (u) * 8192 + tid * 16);                    \
  } while (0)

  // ---- prologue: tile0 full (8 units) + tile1's ph3/ph4-class units (4) ----
  STAGE_A(0, 0, 0); STAGE_A(0, 0, 1); STAGE_A(0, 0, 2); STAGE_A(0, 0, 3);
  STAGE_B(0, 0, 0); STAGE_B(0, 0, 1); STAGE_B(0, 0, 2); STAGE_B(0, 0, 3);
  if (NT > 1) {
    STAGE_A(1, 1, 0); STAGE_A(1, 1, 1);
    STAGE_B(1, 1, 2); STAGE_B(1, 1, 3);
    asm volatile("s_waitcnt vmcnt(4)" ::: "memory");
  } else {
    asm volatile("s_waitcnt vmcnt(0)" ::: "memory");
  }
  __builtin_amdgcn_s_barrier();
  __builtin_amdgcn_sched_barrier(0);

#define PHASE(QM, QN, STAGES)                                                         \
  do {                                                                                \
    const char* Lb_ = lds + buf * 65536;                                              \
    bf16x8 af_[4][2], bb_[2][2];                                                      \
    _Pragma("unroll") for (int mf = 0; mf < 4; ++mf)                                  \
        _Pragma("unroll") for (int ks = 0; ks < 2; ++ks) {                            \
      int row_ = (QM) * 128 + wr * 64 + mf * 16 + (lane & 15);                        \
      int in_ = (ks * 64 + ((lane >> 4) << 4)) ^ ((row_ & 7) << 4);                   \
      af_[mf][ks] = *(const bf16x8*)(Lb_ + row_ * 128 + in_);                         \
    }                                                                                 \
    _Pragma("unroll") for (int nf = 0; nf < 2; ++nf)                                  \
        _Pragma("unroll") for (int ks = 0; ks < 2; ++ks) {                            \
      int c_ = wc * 64 + (QN) * 32 + nf * 16 + (lane & 15);                           \
      int rr_ = ((c_ >> 5) & 1) * 128 + ((c_ >> 6) & 3) * 32 + (c_ & 31);             \
      int in_ = (ks * 64 + ((lane >> 4) << 4)) ^ ((rr_ & 7) << 4);                    \
      bb_[nf][ks] = *(const bf16x8*)(Lb_ + 32768 + rr_ * 128 + in_);                  \
    }                                                                                 \
    STAGES;                                                                           \
    __builtin_amdgcn_s_barrier();                                                     \
    asm volatile("s_waitcnt lgkmcnt(0)" ::: "memory");                                \
    __builtin_amdgcn_sched_barrier(0);                                                \
    __builtin_amdgcn_s_setprio(1);                                                    \
    _Pragma("unroll") for (int mf = 0; mf < 4; ++mf)                                  \
        _Pragma("unroll") for (int nf = 0; nf < 2; ++nf)                              \
            _Pragma("unroll") for (int ks = 0; ks < 2; ++ks)                          \
                acc[QM][QN][mf][nf] = __builtin_amdgcn_mfma_f32_16x16x32_bf16(        \
                    af_[mf][ks], bb_[nf][ks], acc[QM][QN][mf][nf], 0, 0, 0);          \
    __builtin_amdgcn_s_setprio(0);                                                    \
  } while (0)

  for (int t = 0; t < NT; ++t) {
    const int buf = t & 1;
    const int pb = buf ^ 1;
    // ph1 (0,0): stage A(t+1) upper half -> other buffer
    PHASE(0, 0, { if (t + 1 < NT) { STAGE_A(t + 1, pb, 2); STAGE_A(t + 1, pb, 3); } });
    __builtin_amdgcn_s_barrier();
    // ph2 (0,1): stage B(t+1) lower half -> other buffer
    PHASE(0, 1, { if (t + 1 < NT) { STAGE_B(t + 1, pb, 0); STAGE_B(t + 1, pb, 1); } });
    __builtin_amdgcn_s_barrier();
    // ph3 (1,1): stage A(t+2) lower half -> THIS buffer (A-lower last read ph2)
    PHASE(1, 1, { if (t + 2 < NT) { STAGE_A(t + 2, buf, 0); STAGE_A(t + 2, buf, 1); } });
    __builtin_amdgcn_s_barrier();
    // ph4 (1,0): stage B(t+2) upper half -> THIS buffer (B-upper last read ph3)
    PHASE(1, 0, { if (t + 2 < NT) { STAGE_B(t + 2, buf, 2); STAGE_B(t + 2, buf, 3); } });
    // boundary: counted vmcnt (T4) — leave t+2's 4 loads in flight; then barrier
    if (t + 2 < NT) {
      asm volatile("s_waitcnt vmcnt(4)" ::: "memory");
    } else {
      asm volatile("s_waitcnt vmcnt(0)" ::: "memory");
    }
    __builtin_amdgcn_s_barrier();
    __builtin_amdgcn_sched_barrier(0);
  }

  // ---- epilogue: C write, optional fused RoPE on 64-col rope strips ----
  const int colbase = bn * 256 + wc * 64;
  const int rbase = bm * 256 + wr * 64 + ((lane >> 4) << 2);
  const bool isrope = rope && ((colbase % 192) == 128);
  if (isrope) {
#pragma unroll
    for (int qm = 0; qm < 2; ++qm)
#pragma unroll
      for (int mf = 0; mf < 4; ++mf)
#pragma unroll
        for (int nf = 0; nf < 2; ++nf) {
          int i_ = nf * 16 + (lane & 15);
#pragma unroll
          for (int r = 0; r < 4; ++r) {
            int trow = rbase + qm * 128 + mf * 16 + r;
            float c1 = cs[trow * 64 + i_], s1 = sn[trow * 64 + i_];
            float c2 = cs[trow * 64 + 32 + i_], s2 = sn[trow * 64 + 32 + i_];
            float a = acc[qm][0][mf][nf][r], b = acc[qm][1][mf][nf][r];
            C[(size_t)trow * ldc + colbase + i_] = a * c1 - b * s1;
            C[(size_t)trow * ldc + colbase + 32 + i_] = b * c2 + a * s2;
          }
        }
  } else {
#pragma unroll
    for (int qm = 0; qm < 2; ++qm)
#pragma unroll
      for (int qn = 0; qn < 2; ++qn)
#pragma unroll
        for (int mf = 0; mf < 4; ++mf)
#pragma unroll
          for (int nf = 0; nf < 2; ++nf)
#pragma unroll
            for (int r = 0; r < 4; ++r) {
              int trow = rbase + qm * 128 + mf * 16 + r;
              C[(size_t)trow * ldc + colbase + qn * 32 + nf * 16 + (lane & 15)] =
                  acc[qm][qn][mf][nf][r];
            }
  }
#undef PHASE
#undef STAGE_A
#undef STAGE_B
}

// ---- 128x128 bf16 GEMM (m97 structure) for GEMM1+3: A (M,K), B (N,K), C fp32 ----
__global__ __launch_bounds__(256, 2) void gemm128(
    const unsigned short* __restrict__ A, const unsigned short* __restrict__ B,
    float* __restrict__ C, int K, int ldc, int Nvalid) {
  __shared__ __attribute__((aligned(128))) unsigned short As[128 * 32];
  __shared__ __attribute__((aligned(128))) unsigned short Bs[128 * 32];
  const int tid = threadIdx.x;
  const int lane = tid & 63;
  const int wid = tid >> 6;
  const int wr = wid >> 1, wc = wid & 1;
  const int bm = blockIdx.y, bn = blockIdx.x;
  const size_t abase = (size_t)bm * 128 * K;
  const size_t bbase = (size_t)bn * 128 * K;

  f32x4 acc[4][4];
  const f32x4 zero4 = {0.f, 0.f, 0.f, 0.f};
#pragma unroll
  for (int m = 0; m < 4; ++m)
#pragma unroll
    for (int n = 0; n < 4; ++n) acc[m][n] = zero4;

  const int r0 = tid >> 2;
  const int c0 = (tid & 3) * 8;

  for (int k0 = 0; k0 < K; k0 += 32) {
    gload16(A + abase + (size_t)r0 * K + k0 + c0, As + tid * 8);
    gload16(A + abase + (size_t)(r0 + 64) * K + k0 + c0, As + (256 + tid) * 8);
    gload16(B + bbase + (size_t)r0 * K + k0 + c0, Bs + tid * 8);
    gload16(B + bbase + (size_t)(r0 + 64) * K + k0 + c0, Bs + (256 + tid) * 8);
    __syncthreads();
    bf16x8 af[4], bfr[4];
#pragma unroll
    for (int m = 0; m < 4; ++m)
      af[m] = *(const bf16x8*)(As + (wr * 64 + m * 16 + (lane & 15)) * 32 + (lane >> 4) * 8);
#pragma unroll
    for (int n = 0; n < 4; ++n)
      bfr[n] = *(const bf16x8*)(Bs + (wc * 64 + n * 16 + (lane & 15)) * 32 + (lane >> 4) * 8);
#pragma unroll
    for (int m = 0; m < 4; ++m)
#pragma unroll
      for (int n = 0; n < 4; ++n)
        acc[m][n] = __builtin_amdgcn_mfma_f32_16x16x32_bf16(af[m], bfr[n], acc[m][n], 0, 0, 0);
    __syncthreads();
  }

  const int crow0 = bm * 128 + wr * 64 + ((lane >> 4) << 2);
  const int ccol0 = bn * 128 + wc * 64 + (lane & 15);
#pragma unroll
  for (int m = 0; m < 4; ++m) {
#pragma unroll
    for (int n = 0; n < 4; ++n) {
      int col = ccol0 + n * 16;
      if (col < Nvalid) {
#pragma unroll
        for (int r = 0; r < 4; ++r) {
          int row = crow0 + m * 16 + r;
          C[(size_t)row * ldc + col] = acc[m][n][r];
        }
      }
    }
  }
}

// ---- rmsnorm over cq rows (1536), raw stride 2176, out bf16 ----
__global__ void rmsnorm_cq(const float* __restrict__ raw, const float* __restrict__ gamma,
                           unsigned short* __restrict__ out) {
  __shared__ float red[4];
  int t = blockIdx.x, tid = threadIdx.x;
  const float* r = raw + (size_t)t * 2176;
  float v[6];
  float ss = 0.f;
#pragma unroll
  for (int i = 0; i < 6; ++i) {
    v[i] = r[tid + i * 256];
    ss += v[i] * v[i];
  }
#pragma unroll
  for (int o = 32; o > 0; o >>= 1) ss += __shfl_xor(ss, o, 64);
  if ((tid & 63) == 0) red[tid >> 6] = ss;
  __syncthreads();
  ss = red[0] + red[1] + red[2] + red[3];
  float sc = rsqrtf(ss * (1.f / 1536.f) + 1e-6f);
#pragma unroll
  for (int i = 0; i < 6; ++i)
    out[(size_t)t * 1536 + tid + i * 256] = f2bf(v[i] * sc * gamma[tid + i * 256]);
}

// ---- kv epilogue: rmsnorm(kv[:512]) + rope(kv[512:576]) -> out cols 24576..25152 ----
__global__ void kv_epi(const float* __restrict__ raw, const float* __restrict__ gamma,
                       const float* __restrict__ cs, const float* __restrict__ sn,
                       float* __restrict__ out) {
  __shared__ float red[4];
  int t = blockIdx.x, tid = threadIdx.x;
  const float* r = raw + (size_t)t * 2176 + 1536;
  float v0 = r[tid], v1 = r[tid + 256];
  float ss = v0 * v0 + v1 * v1;
#pragma unroll
  for (int o = 32; o > 0; o >>= 1) ss += __shfl_xor(ss, o, 64);
  if ((tid & 63) == 0) red[tid >> 6] = ss;
  __syncthreads();
  ss = red[0] + red[1] + red[2] + red[3];
  float sc = rsqrtf(ss * (1.f / 512.f) + 1e-6f);
  float* orow = out + (size_t)t * OUT_LD + 24576;
  orow[tid] = v0 * sc * gamma[tid];
  orow[tid + 256] = v1 * sc * gamma[tid + 256];
  if (tid < 32) {
    float a = r[512 + tid], b = r[544 + tid];
    orow[512 + tid] = a * cs[t * 64 + tid] - b * sn[t * 64 + tid];
    orow[544 + tid] = b * cs[t * 64 + 32 + tid] + a * sn[t * 64 + 32 + tid];
  }
}

extern "C" void kernel_launch(void* const* d_in, const int* in_sizes, int n_in,
                              void* d_out, int out_size, void* d_ws, size_t ws_size,
                              hipStream_t stream) {
  const float* token_x = (const float*)d_in[0];   // 4096 x 7168
  const float* wq_a = (const float*)d_in[1];      // 7168 x 1536
  const float* wq_b = (const float*)d_in[2];      // 1536 x 24576
  const float* wkv = (const float*)d_in[3];       // 7168 x 576
  const float* rope_cos = (const float*)d_in[4];  // 4096 x 64
  const float* rope_sin = (const float*)d_in[5];
  const float* gamma_cq = (const float*)d_in[6];   // 1536
  const float* gamma_ckv = (const float*)d_in[7];  // 512
  float* out = (float*)d_out;                      // 4096 x 25152

  char* ws = (char*)d_ws;
  unsigned short* txb = (unsigned short*)ws;                          // 4096x7168 bf16
  unsigned short* wqbT = (unsigned short*)(ws + 58720256);            // 24576x1536 bf16
  unsigned short* Bc = (unsigned short*)(ws + 134217728);             // 2176x7168 bf16
  float* raw = (float*)(ws + 165412864);                              // 4096x2176 f32
  unsigned short* cqb = (unsigned short*)(ws + 201064448);            // 4096x1536 bf16

  // 1) conversions
  cvt_bf16<<<28672, 256, 0, stream>>>(token_x, txb);
  transpose_cvt<<<dim3(7168 / 32, 1536 / 32), dim3(32, 8), 0, stream>>>(wq_a, Bc, 7168, 1536, 1536);
  transpose_cvt<<<dim3(7168 / 32, 640 / 32), dim3(32, 8), 0, stream>>>(
      wkv, Bc + (size_t)1536 * 7168, 7168, 576, 640);
  transpose_cvt<<<dim3(1536 / 32, 24576 / 32), dim3(32, 8), 0, stream>>>(wq_b, wqbT, 1536, 24576, 24576);

  // 2) fused GEMM1+GEMM3: raw = token_x @ [wq_a | wkv | 0pad]  (4096 x 2176, K=7168)
  gemm128<<<dim3(17, 32), 256, 0, stream>>>(txb, Bc, raw, 7168, 2176, 2176);

  // 3) epilogues of stage 1
  rmsnorm_cq<<<4096, 256, 0, stream>>>(raw, gamma_cq, cqb);
  kv_epi<<<4096, 256, 0, stream>>>(raw, gamma_ckv, rope_cos, rope_sin, out);

  // 4) GEMM2 (8-phase 256^2, fused rope): q = cq @ wq_b -> out cols [0, 24576), K=1536
  //    grid = 16 Mtiles * 96 Ntiles = 1536 (% 8 == 0 for XCD swizzle)
  gemm256<<<1536, 512, 0, stream>>>(cqb, wqbT, out, 1536, OUT_LD, 16, rope_cos, rope_sin, 1);
}

// Round 5
// 699.776 us; speedup vs baseline: 1.1728x; 1.0466x over previous
//
#include <hip/hip_runtime.h>

// MLA projection: T=4096, H=7168, N_HEADS=128, QK_NOPE=128, QK_ROPE=64, KV_RANK=512
// out row = [q (128*192=24576) | ckv (512) | k_rope (64)] = 25152 fp32

typedef __attribute__((ext_vector_type(8))) __bf16 bf16x8;
typedef __attribute__((ext_vector_type(4))) float f32x4;

#define OUT_LD 25152

__device__ __forceinline__ unsigned short f2bf(float f) {
  union { float f; unsigned u; } v; v.f = f;
  unsigned r = v.u + 0x7FFFu + ((v.u >> 16) & 1u);  // RNE
  return (unsigned short)(r >> 16);
}

__device__ __forceinline__ void gload16(const void* g, void* l) {
  __builtin_amdgcn_global_load_lds(
      (__attribute__((address_space(1))) void*)(void*)g,
      (__attribute__((address_space(3))) void*)l, 16, 0, 0);
}

// ---- fp32 -> bf16 straight conversion (token_x), 4 elems/thread ----
__global__ void cvt_bf16(const float* __restrict__ in, unsigned short* __restrict__ out) {
  size_t i = (size_t)blockIdx.x * 256 + threadIdx.x;
  float4 f = ((const float4*)in)[i];
  ushort4 o;
  o.x = f2bf(f.x); o.y = f2bf(f.y); o.z = f2bf(f.z); o.w = f2bf(f.w);
  ((ushort4*)out)[i] = o;
}

// ---- fp32 (K x N) -> bf16 (Npad x K) transpose+convert, zero pad rows >= N ----
__global__ void transpose_cvt(const float* __restrict__ in, unsigned short* __restrict__ out,
                              int K, int N, int Npad) {
  __shared__ float tile[32][33];
  int k0 = blockIdx.x * 32, n0 = blockIdx.y * 32;
  int tx = threadIdx.x, ty = threadIdx.y;  // 32 x 8
#pragma unroll
  for (int i = 0; i < 4; ++i) {
    int k = k0 + ty + i * 8;
    int n = n0 + tx;
    tile[ty + i * 8][tx] = (n < N) ? in[(size_t)k * N + n] : 0.f;
  }
  __syncthreads();
#pragma unroll
  for (int i = 0; i < 4; ++i) {
    int n = n0 + ty + i * 8;
    int k = k0 + tx;
    if (n < Npad) out[(size_t)n * K + k] = f2bf(tile[tx][ty + i * 8]);
  }
}

// ======================================================================
// 256x256 8-phase GEMM, round-5 revision: fragment REUSE across phases
// (24 ds_read_b128/iter instead of 48) + hoisted reads gated by COUNTED
// lgkmcnt so LDS service overlaps MFMA bursts. T1 XCD swizzle, T2 3-bit
// XOR swizzle (conflict-free, verified 0 in r4), T4 counted vmcnt, T5
// setprio. A (M,K) k-contig, B (N,K) k-contig, C fp32.
// 512 threads = 8 waves (2 M x 4 N). BK=64. LDS 128 KiB (2 dbuf).
// ======================================================================
__global__ __launch_bounds__(512, 2) void gemm256(
    const unsigned short* __restrict__ A, const unsigned short* __restrict__ B,
    float* __restrict__ C, int K, int ldc, int Mtiles,
    const float* __restrict__ cs, const float* __restrict__ sn, int rope) {
  __shared__ __attribute__((aligned(128))) char lds[131072];
  const int tid = threadIdx.x;
  const int lane = tid & 63;
  const int wr = (tid >> 6) >> 2;  // 0..1
  const int wc = (tid >> 6) & 3;   // 0..3
  const int NT = K >> 6;

  // T1: XCD-aware block swizzle (grid % 8 == 0 by launch)
  const int nwg = gridDim.x;
  const int per = nwg >> 3;
  const int bid = blockIdx.x;
  const int swz = (bid & 7) * per + (bid >> 3);
  const int bm = swz % Mtiles, bn = swz / Mtiles;

  // staging geometry: thread covers 16 B at linear LDS byte tid*16;
  // ldsrow = tid>>3, chunk = tid&7; source col pre-swizzled (rule #21)
  const int strow = tid >> 3;
  const int stcolb = (((tid & 7) ^ ((tid >> 3) & 7)) << 4);
  const size_t abase = (size_t)(bm * 256) * K;
  const size_t bbase = (size_t)(bn * 256) * K;

  f32x4 acc[2][2][4][2];
  const f32x4 z4 = {0.f, 0.f, 0.f, 0.f};
#pragma unroll
  for (int a = 0; a < 2; ++a)
#pragma unroll
    for (int b = 0; b < 2; ++b)
#pragma unroll
      for (int c = 0; c < 4; ++c)
#pragma unroll
        for (int d = 0; d < 2; ++d) acc[a][b][c][d] = z4;

// A LDS: region buf*65536 + 0,     rows 0..255 natural (row = m), 128 B/row
// B LDS: region buf*65536 + 32768, rows permuted: ldsrow(n) = ((n>>5)&1)*128 + ((n>>6)&3)*32 + (n&31)
#define STAGE_A(kt, bsel, u)                                                          \
  do {                                                                                \
    int row_ = (u) * 64 + strow;                                                      \
    gload16((const char*)(A + abase + (size_t)row_ * K + (size_t)(kt) * 64) + stcolb, \
            lds + (bsel) * 65536 + (u) * 8192 + tid * 16);                            \
  } while (0)
#define STAGE_B(kt, bsel, u)                                                          \
  do {                                                                                \
    int lrow_ = (u) * 64 + strow;                                                     \
    int n_ = ((lrow_ >> 5) & 3) * 64 + ((lrow_ >> 7) & 1) * 32 + (lrow_ & 31);        \
    gload16((const char*)(B + bbase + (size_t)n_ * K + (size_t)(kt) * 64) + stcolb,   \
            lds + (bsel) * 65536 + 32768 + (u) * 8192 + tid * 16);                    \
  } while (0)

#define READ_A(dst, QM)                                                     \
  do {                                                                      \
    _Pragma("unroll") for (int mf = 0; mf < 4; ++mf)                        \
        _Pragma("unroll") for (int ks = 0; ks < 2; ++ks) {                  \
      int row_ = (QM) * 128 + wr * 64 + mf * 16 + (lane & 15);              \
      int in_ = (ks * 64 + ((lane >> 4) << 4)) ^ ((row_ & 7) << 4);         \
      dst[mf][ks] = *(const bf16x8*)(Lb + row_ * 128 + in_);                \
    }                                                                       \
  } while (0)
#define READ_B(dst, QN)                                                     \
  do {                                                                      \
    _Pragma("unroll") for (int nf = 0; nf < 2; ++nf)                        \
        _Pragma("unroll") for (int ks = 0; ks < 2; ++ks) {                  \
      int c_ = wc * 64 + (QN) * 32 + nf * 16 + (lane & 15);                 \
      int rr_ = ((c_ >> 5) & 1) * 128 + ((c_ >> 6) & 3) * 32 + (c_ & 31);   \
      int in_ = (ks * 64 + ((lane >> 4) << 4)) ^ ((rr_ & 7) << 4);          \
      dst[nf][ks] = *(const bf16x8*)(Lb + 32768 + rr_ * 128 + in_);         \
    }                                                                       \
  } while (0)
#define MFMA_Q(QM, QN, AF, BB)                                              \
  do {                                                                      \
    __builtin_amdgcn_s_setprio(1);                                          \
    _Pragma("unroll") for (int mf = 0; mf < 4; ++mf)                        \
        _Pragma("unroll") for (int nf = 0; nf < 2; ++nf)                    \
            _Pragma("unroll") for (int ks = 0; ks < 2; ++ks)                \
                acc[QM][QN][mf][nf] = __builtin_amdgcn_mfma_f32_16x16x32_bf16( \
                    AF[mf][ks], BB[nf][ks], acc[QM][QN][mf][nf], 0, 0, 0);  \
    __builtin_amdgcn_s_setprio(0);                                          \
  } while (0)

  // ---- prologue: tile0 full (8 units) + tile1's ph3/ph4-class units (4) ----
  STAGE_A(0, 0, 0); STAGE_A(0, 0, 1); STAGE_A(0, 0, 2); STAGE_A(0, 0, 3);
  STAGE_B(0, 0, 0); STAGE_B(0, 0, 1); STAGE_B(0, 0, 2); STAGE_B(0, 0, 3);
  if (NT > 1) {
    STAGE_A(1, 1, 0); STAGE_A(1, 1, 1);
    STAGE_B(1, 1, 2); STAGE_B(1, 1, 3);
    asm volatile("s_waitcnt vmcnt(4)" ::: "memory");
  } else {
    asm volatile("s_waitcnt vmcnt(0)" ::: "memory");
  }
  __builtin_amdgcn_s_barrier();
  __builtin_amdgcn_sched_barrier(0);

  for (int t = 0; t < NT; ++t) {
    const int buf = t & 1;
    const int pb = buf ^ 1;
    const char* Lb = lds + buf * 65536;
    bf16x8 af0[4][2], af1[4][2], bb0[2][2], bb1[2][2];

    // top-of-iter: issue af0(8) + bb0(4), pin order, then bb1(4) -> 16 outstanding
    READ_A(af0, 0);
    READ_B(bb0, 0);
    __builtin_amdgcn_sched_barrier(0);  // pin: af0+bb0 issued before bb1
    READ_B(bb1, 1);

    // ---- ph1: quadrant (0,0) ----
    if (t + 1 < NT) { STAGE_A(t + 1, pb, 2); STAGE_A(t + 1, pb, 3); }
    __builtin_amdgcn_s_barrier();
    asm volatile("s_waitcnt lgkmcnt(4)" ::: "memory");  // af0+bb0 done; bb1 in flight
    __builtin_amdgcn_sched_barrier(0);
    MFMA_Q(0, 0, af0, bb0);
    __builtin_amdgcn_s_barrier();

    // ---- ph2: quadrant (0,1) ----
    if (t + 1 < NT) { STAGE_B(t + 1, pb, 0); STAGE_B(t + 1, pb, 1); }
    __builtin_amdgcn_s_barrier();
    asm volatile("s_waitcnt lgkmcnt(0)" ::: "memory");  // bb1 done
    __builtin_amdgcn_sched_barrier(0);
    READ_A(af1, 1);  // issue af1(8): overlaps ph2 MFMA + ph3 stage/barrier
    MFMA_Q(0, 1, af0, bb1);
    __builtin_amdgcn_s_barrier();

    // ---- ph3: quadrant (1,1) ----
    // STAGE into buf A-lower: safe — every wave passed ph2's lgkmcnt(0) (all af0/bb reads done)
    if (t + 2 < NT) { STAGE_A(t + 2, buf, 0); STAGE_A(t + 2, buf, 1); }
    __builtin_amdgcn_s_barrier();
    asm volatile("s_waitcnt lgkmcnt(0)" ::: "memory");  // af1 done
    __builtin_amdgcn_sched_barrier(0);
    MFMA_Q(1, 1, af1, bb1);
    __builtin_amdgcn_s_barrier();

    // ---- ph4: quadrant (1,0) — zero new LDS reads (af1+bb0 live) ----
    // STAGE into buf B-upper (bb1 rows): safe — all waves passed ph3's lgkmcnt(0)
    if (t + 2 < NT) { STAGE_B(t + 2, buf, 2); STAGE_B(t + 2, buf, 3); }
    __builtin_amdgcn_s_barrier();
    MFMA_Q(1, 0, af1, bb0);

    // boundary: counted vmcnt (T4) — t+1's 4 units (into pb) drained, t+2's 4 in flight
    if (t + 2 < NT) {
      asm volatile("s_waitcnt vmcnt(4)" ::: "memory");
    } else {
      asm volatile("s_waitcnt vmcnt(0)" ::: "memory");
    }
    __builtin_amdgcn_s_barrier();
    __builtin_amdgcn_sched_barrier(0);
  }

  // ---- epilogue: C write, optional fused RoPE on 64-col rope strips ----
  const int colbase = bn * 256 + wc * 64;
  const int rbase = bm * 256 + wr * 64 + ((lane >> 4) << 2);
  const bool isrope = rope && ((colbase % 192) == 128);
  if (isrope) {
#pragma unroll
    for (int qm = 0; qm < 2; ++qm)
#pragma unroll
      for (int mf = 0; mf < 4; ++mf)
#pragma unroll
        for (int nf = 0; nf < 2; ++nf) {
          int i_ = nf * 16 + (lane & 15);
#pragma unroll
          for (int r = 0; r < 4; ++r) {
            int trow = rbase + qm * 128 + mf * 16 + r;
            float c1 = cs[trow * 64 + i_], s1 = sn[trow * 64 + i_];
            float c2 = cs[trow * 64 + 32 + i_], s2 = sn[trow * 64 + 32 + i_];
            float a = acc[qm][0][mf][nf][r], b = acc[qm][1][mf][nf][r];
            C[(size_t)trow * ldc + colbase + i_] = a * c1 - b * s1;
            C[(size_t)trow * ldc + colbase + 32 + i_] = b * c2 + a * s2;
          }
        }
  } else {
#pragma unroll
    for (int qm = 0; qm < 2; ++qm)
#pragma unroll
      for (int qn = 0; qn < 2; ++qn)
#pragma unroll
        for (int mf = 0; mf < 4; ++mf)
#pragma unroll
          for (int nf = 0; nf < 2; ++nf)
#pragma unroll
            for (int r = 0; r < 4; ++r) {
              int trow = rbase + qm * 128 + mf * 16 + r;
              C[(size_t)trow * ldc + colbase + qn * 32 + nf * 16 + (lane & 15)] =
                  acc[qm][qn][mf][nf][r];
            }
  }
#undef MFMA_Q
#undef READ_B
#undef READ_A
#undef STAGE_B
#undef STAGE_A
}

// ---- 128x128 bf16 GEMM (m97 structure) for GEMM1+3: A (M,K), B (N,K), C fp32 ----
__global__ __launch_bounds__(256, 2) void gemm128(
    const unsigned short* __restrict__ A, const unsigned short* __restrict__ B,
    float* __restrict__ C, int K, int ldc, int Nvalid) {
  __shared__ __attribute__((aligned(128))) unsigned short As[128 * 32];
  __shared__ __attribute__((aligned(128))) unsigned short Bs[128 * 32];
  const int tid = threadIdx.x;
  const int lane = tid & 63;
  const int wid = tid >> 6;
  const int wr = wid >> 1, wc = wid & 1;
  const int bm = blockIdx.y, bn = blockIdx.x;
  const size_t abase = (size_t)bm * 128 * K;
  const size_t bbase = (size_t)bn * 128 * K;

  f32x4 acc[4][4];
  const f32x4 zero4 = {0.f, 0.f, 0.f, 0.f};
#pragma unroll
  for (int m = 0; m < 4; ++m)
#pragma unroll
    for (int n = 0; n < 4; ++n) acc[m][n] = zero4;

  const int r0 = tid >> 2;
  const int c0 = (tid & 3) * 8;

  for (int k0 = 0; k0 < K; k0 += 32) {
    gload16(A + abase + (size_t)r0 * K + k0 + c0, As + tid * 8);
    gload16(A + abase + (size_t)(r0 + 64) * K + k0 + c0, As + (256 + tid) * 8);
    gload16(B + bbase + (size_t)r0 * K + k0 + c0, Bs + tid * 8);
    gload16(B + bbase + (size_t)(r0 + 64) * K + k0 + c0, Bs + (256 + tid) * 8);
    __syncthreads();
    bf16x8 af[4], bfr[4];
#pragma unroll
    for (int m = 0; m < 4; ++m)
      af[m] = *(const bf16x8*)(As + (wr * 64 + m * 16 + (lane & 15)) * 32 + (lane >> 4) * 8);
#pragma unroll
    for (int n = 0; n < 4; ++n)
      bfr[n] = *(const bf16x8*)(Bs + (wc * 64 + n * 16 + (lane & 15)) * 32 + (lane >> 4) * 8);
#pragma unroll
    for (int m = 0; m < 4; ++m)
#pragma unroll
      for (int n = 0; n < 4; ++n)
        acc[m][n] = __builtin_amdgcn_mfma_f32_16x16x32_bf16(af[m], bfr[n], acc[m][n], 0, 0, 0);
    __syncthreads();
  }

  const int crow0 = bm * 128 + wr * 64 + ((lane >> 4) << 2);
  const int ccol0 = bn * 128 + wc * 64 + (lane & 15);
#pragma unroll
  for (int m = 0; m < 4; ++m) {
#pragma unroll
    for (int n = 0; n < 4; ++n) {
      int col = ccol0 + n * 16;
      if (col < Nvalid) {
#pragma unroll
        for (int r = 0; r < 4; ++r) {
          int row = crow0 + m * 16 + r;
          C[(size_t)row * ldc + col] = acc[m][n][r];
        }
      }
    }
  }
}

// ---- rmsnorm over cq rows (1536), raw stride 2176, out bf16 ----
__global__ void rmsnorm_cq(const float* __restrict__ raw, const float* __restrict__ gamma,
                           unsigned short* __restrict__ out) {
  __shared__ float red[4];
  int t = blockIdx.x, tid = threadIdx.x;
  const float* r = raw + (size_t)t * 2176;
  float v[6];
  float ss = 0.f;
#pragma unroll
  for (int i = 0; i < 6; ++i) {
    v[i] = r[tid + i * 256];
    ss += v[i] * v[i];
  }
#pragma unroll
  for (int o = 32; o > 0; o >>= 1) ss += __shfl_xor(ss, o, 64);
  if ((tid & 63) == 0) red[tid >> 6] = ss;
  __syncthreads();
  ss = red[0] + red[1] + red[2] + red[3];
  float sc = rsqrtf(ss * (1.f / 1536.f) + 1e-6f);
#pragma unroll
  for (int i = 0; i < 6; ++i)
    out[(size_t)t * 1536 + tid + i * 256] = f2bf(v[i] * sc * gamma[tid + i * 256]);
}

// ---- kv epilogue: rmsnorm(kv[:512]) + rope(kv[512:576]) -> out cols 24576..25152 ----
__global__ void kv_epi(const float* __restrict__ raw, const float* __restrict__ gamma,
                       const float* __restrict__ cs, const float* __restrict__ sn,
                       float* __restrict__ out) {
  __shared__ float red[4];
  int t = blockIdx.x, tid = threadIdx.x;
  const float* r = raw + (size_t)t * 2176 + 1536;
  float v0 = r[tid], v1 = r[tid + 256];
  float ss = v0 * v0 + v1 * v1;
#pragma unroll
  for (int o = 32; o > 0; o >>= 1) ss += __shfl_xor(ss, o, 64);
  if ((tid & 63) == 0) red[tid >> 6] = ss;
  __syncthreads();
  ss = red[0] + red[1] + red[2] + red[3];
  float sc = rsqrtf(ss * (1.f / 512.f) + 1e-6f);
  float* orow = out + (size_t)t * OUT_LD + 24576;
  orow[tid] = v0 * sc * gamma[tid];
  orow[tid + 256] = v1 * sc * gamma[tid + 256];
  if (tid < 32) {
    float a = r[512 + tid], b = r[544 + tid];
    orow[512 + tid] = a * cs[t * 64 + tid] - b * sn[t * 64 + tid];
    orow[544 + tid] = b * cs[t * 64 + 32 + tid] + a * sn[t * 64 + 32 + tid];
  }
}

extern "C" void kernel_launch(void* const* d_in, const int* in_sizes, int n_in,
                              void* d_out, int out_size, void* d_ws, size_t ws_size,
                              hipStream_t stream) {
  const float* token_x = (const float*)d_in[0];   // 4096 x 7168
  const float* wq_a = (const float*)d_in[1];      // 7168 x 1536
  const float* wq_b = (const float*)d_in[2];      // 1536 x 24576
  const float* wkv = (const float*)d_in[3];       // 7168 x 576
  const float* rope_cos = (const float*)d_in[4];  // 4096 x 64
  const float* rope_sin = (const float*)d_in[5];
  const float* gamma_cq = (const float*)d_in[6];   // 1536
  const float* gamma_ckv = (const float*)d_in[7];  // 512
  float* out = (float*)d_out;                      // 4096 x 25152

  char* ws = (char*)d_ws;
  unsigned short* txb = (unsigned short*)ws;                          // 4096x7168 bf16
  unsigned short* wqbT = (unsigned short*)(ws + 58720256);            // 24576x1536 bf16
  unsigned short* Bc = (unsigned short*)(ws + 134217728);             // 2176x7168 bf16
  float* raw = (float*)(ws + 165412864);                              // 4096x2176 f32
  unsigned short* cqb = (unsigned short*)(ws + 201064448);            // 4096x1536 bf16

  // 1) conversions
  cvt_bf16<<<28672, 256, 0, stream>>>(token_x, txb);
  transpose_cvt<<<dim3(7168 / 32, 1536 / 32), dim3(32, 8), 0, stream>>>(wq_a, Bc, 7168, 1536, 1536);
  transpose_cvt<<<dim3(7168 / 32, 640 / 32), dim3(32, 8), 0, stream>>>(
      wkv, Bc + (size_t)1536 * 7168, 7168, 576, 640);
  transpose_cvt<<<dim3(1536 / 32, 24576 / 32), dim3(32, 8), 0, stream>>>(wq_b, wqbT, 1536, 24576, 24576);

  // 2) fused GEMM1+GEMM3: raw = token_x @ [wq_a | wkv | 0pad]  (4096 x 2176, K=7168)
  gemm128<<<dim3(17, 32), 256, 0, stream>>>(txb, Bc, raw, 7168, 2176, 2176);

  // 3) epilogues of stage 1
  rmsnorm_cq<<<4096, 256, 0, stream>>>(raw, gamma_cq, cqb);
  kv_epi<<<4096, 256, 0, stream>>>(raw, gamma_ckv, rope_cos, rope_sin, out);

  // 4) GEMM2 (8-phase 256^2, fused rope): q = cq @ wq_b -> out cols [0, 24576), K=1536
  //    grid = 16 Mtiles * 96 Ntiles = 1536 (% 8 == 0 for XCD swizzle)
  gemm256<<<1536, 512, 0, stream>>>(cqb, wqbT, out, 1536, OUT_LD, 16, rope_cos, rope_sin, 1);
}

// Round 6
// 699.202 us; speedup vs baseline: 1.1738x; 1.0008x over previous
//
#include <hip/hip_runtime.h>

// MLA projection: T=4096, H=7168, N_HEADS=128, QK_NOPE=128, QK_ROPE=64, KV_RANK=512
// out row = [q (128*192=24576) | ckv (512) | k_rope (64)] = 25152 fp32

typedef __attribute__((ext_vector_type(8))) __bf16 bf16x8;
typedef __attribute__((ext_vector_type(4))) float f32x4;

#define OUT_LD 25152

__device__ __forceinline__ unsigned short f2bf(float f) {
  union { float f; unsigned u; } v; v.f = f;
  unsigned r = v.u + 0x7FFFu + ((v.u >> 16) & 1u);  // RNE
  return (unsigned short)(r >> 16);
}

__device__ __forceinline__ void gload16(const void* g, void* l) {
  __builtin_amdgcn_global_load_lds(
      (__attribute__((address_space(1))) void*)(void*)g,
      (__attribute__((address_space(3))) void*)l, 16, 0, 0);
}

// ---- fp32 -> bf16 straight conversion (token_x), 4 elems/thread ----
__global__ void cvt_bf16(const float* __restrict__ in, unsigned short* __restrict__ out) {
  size_t i = (size_t)blockIdx.x * 256 + threadIdx.x;
  float4 f = ((const float4*)in)[i];
  ushort4 o;
  o.x = f2bf(f.x); o.y = f2bf(f.y); o.z = f2bf(f.z); o.w = f2bf(f.w);
  ((ushort4*)out)[i] = o;
}

// ---- fp32 (K x N) -> bf16 (Npad x K) transpose+convert, zero pad rows >= N ----
__global__ void transpose_cvt(const float* __restrict__ in, unsigned short* __restrict__ out,
                              int K, int N, int Npad) {
  __shared__ float tile[32][33];
  int k0 = blockIdx.x * 32, n0 = blockIdx.y * 32;
  int tx = threadIdx.x, ty = threadIdx.y;  // 32 x 8
#pragma unroll
  for (int i = 0; i < 4; ++i) {
    int k = k0 + ty + i * 8;
    int n = n0 + tx;
    tile[ty + i * 8][tx] = (n < N) ? in[(size_t)k * N + n] : 0.f;
  }
  __syncthreads();
#pragma unroll
  for (int i = 0; i < 4; ++i) {
    int n = n0 + ty + i * 8;
    int k = k0 + tx;
    if (n < Npad) out[(size_t)n * K + k] = f2bf(tile[tx][ty + i * 8]);
  }
}

// ======================================================================
// 256x256 8-phase GEMM, round-6: EVEN READ DISTRIBUTION via cross-boundary
// af0 prefetch (ph3 reads next iter's af0 from the other buffer) + counted
// lgkmcnt gates. Reads/phase: top 8 (bb0+bb1), ph2 8 (af1), ph3 8 (af0'),
// ph4 0 — all but bb0 overlap MFMA clusters. T1 XCD swizzle, T2 3-bit XOR
// swizzle (0 conflicts), T4 counted vmcnt, T5 setprio.
// A (M,K) k-contig, B (N,K) k-contig, C fp32.
// 512 threads = 8 waves (2 M x 4 N). BK=64. LDS 128 KiB (2 dbuf).
// ======================================================================
__global__ __launch_bounds__(512, 2) void gemm256(
    const unsigned short* __restrict__ A, const unsigned short* __restrict__ B,
    float* __restrict__ C, int K, int ldc, int Mtiles,
    const float* __restrict__ cs, const float* __restrict__ sn, int rope) {
  __shared__ __attribute__((aligned(128))) char lds[131072];
  const int tid = threadIdx.x;
  const int lane = tid & 63;
  const int wr = (tid >> 6) >> 2;  // 0..1
  const int wc = (tid >> 6) & 3;   // 0..3
  const int NT = K >> 6;

  // T1: XCD-aware block swizzle (grid % 8 == 0 by launch)
  const int nwg = gridDim.x;
  const int per = nwg >> 3;
  const int bid = blockIdx.x;
  const int swz = (bid & 7) * per + (bid >> 3);
  const int bm = swz % Mtiles, bn = swz / Mtiles;

  // staging geometry: thread covers 16 B at linear LDS byte tid*16;
  // ldsrow = tid>>3, chunk = tid&7; source col pre-swizzled (rule #21)
  const int strow = tid >> 3;
  const int stcolb = (((tid & 7) ^ ((tid >> 3) & 7)) << 4);
  const size_t abase = (size_t)(bm * 256) * K;
  const size_t bbase = (size_t)(bn * 256) * K;

  f32x4 acc[2][2][4][2];
  const f32x4 z4 = {0.f, 0.f, 0.f, 0.f};
#pragma unroll
  for (int a = 0; a < 2; ++a)
#pragma unroll
    for (int b = 0; b < 2; ++b)
#pragma unroll
      for (int c = 0; c < 4; ++c)
#pragma unroll
        for (int d = 0; d < 2; ++d) acc[a][b][c][d] = z4;

// A LDS: region buf*65536 + 0,     rows 0..255 natural (row = m), 128 B/row
// B LDS: region buf*65536 + 32768, rows permuted: ldsrow(n) = ((n>>5)&1)*128 + ((n>>6)&3)*32 + (n&31)
#define STAGE_A(kt, bsel, u)                                                          \
  do {                                                                                \
    int row_ = (u) * 64 + strow;                                                      \
    gload16((const char*)(A + abase + (size_t)row_ * K + (size_t)(kt) * 64) + stcolb, \
            lds + (bsel) * 65536 + (u) * 8192 + tid * 16);                            \
  } while (0)
#define STAGE_B(kt, bsel, u)                                                          \
  do {                                                                                \
    int lrow_ = (u) * 64 + strow;                                                     \
    int n_ = ((lrow_ >> 5) & 3) * 64 + ((lrow_ >> 7) & 1) * 32 + (lrow_ & 31);        \
    gload16((const char*)(B + bbase + (size_t)n_ * K + (size_t)(kt) * 64) + stcolb,   \
            lds + (bsel) * 65536 + 32768 + (u) * 8192 + tid * 16);                    \
  } while (0)

#define READ_A(dst, QM, LBASE)                                              \
  do {                                                                      \
    _Pragma("unroll") for (int mf = 0; mf < 4; ++mf)                        \
        _Pragma("unroll") for (int ks = 0; ks < 2; ++ks) {                  \
      int row_ = (QM) * 128 + wr * 64 + mf * 16 + (lane & 15);              \
      int in_ = (ks * 64 + ((lane >> 4) << 4)) ^ ((row_ & 7) << 4);         \
      dst[mf][ks] = *(const bf16x8*)((LBASE) + row_ * 128 + in_);           \
    }                                                                       \
  } while (0)
#define READ_B(dst, QN, LBASE)                                              \
  do {                                                                      \
    _Pragma("unroll") for (int nf = 0; nf < 2; ++nf)                        \
        _Pragma("unroll") for (int ks = 0; ks < 2; ++ks) {                  \
      int c_ = wc * 64 + (QN) * 32 + nf * 16 + (lane & 15);                 \
      int rr_ = ((c_ >> 5) & 1) * 128 + ((c_ >> 6) & 3) * 32 + (c_ & 31);   \
      int in_ = (ks * 64 + ((lane >> 4) << 4)) ^ ((rr_ & 7) << 4);          \
      dst[nf][ks] = *(const bf16x8*)((LBASE) + 32768 + rr_ * 128 + in_);    \
    }                                                                       \
  } while (0)
#define MFMA_Q(QM, QN, AF, BB)                                              \
  do {                                                                      \
    __builtin_amdgcn_s_setprio(1);                                          \
    _Pragma("unroll") for (int mf = 0; mf < 4; ++mf)                        \
        _Pragma("unroll") for (int nf = 0; nf < 2; ++nf)                    \
            _Pragma("unroll") for (int ks = 0; ks < 2; ++ks)                \
                acc[QM][QN][mf][nf] = __builtin_amdgcn_mfma_f32_16x16x32_bf16( \
                    AF[mf][ks], BB[nf][ks], acc[QM][QN][mf][nf], 0, 0, 0);  \
    __builtin_amdgcn_s_setprio(0);                                          \
  } while (0)

  // ---- prologue: tile0 full (8 units) + tile1's ph3/ph4-class units (4) ----
  STAGE_A(0, 0, 0); STAGE_A(0, 0, 1); STAGE_A(0, 0, 2); STAGE_A(0, 0, 3);
  STAGE_B(0, 0, 0); STAGE_B(0, 0, 1); STAGE_B(0, 0, 2); STAGE_B(0, 0, 3);
  if (NT > 1) {
    STAGE_A(1, 1, 0); STAGE_A(1, 1, 1);
    STAGE_B(1, 1, 2); STAGE_B(1, 1, 3);
    asm volatile("s_waitcnt vmcnt(4)" ::: "memory");
  } else {
    asm volatile("s_waitcnt vmcnt(0)" ::: "memory");
  }
  __builtin_amdgcn_s_barrier();
  __builtin_amdgcn_sched_barrier(0);

  bf16x8 af0[4][2], af1[4][2], bb0[2][2], bb1[2][2];
  // prologue read: af0 of tile0 (buf0) — matches the steady-state ph3 prefetch slot
  READ_A(af0, 0, lds);
  __builtin_amdgcn_sched_barrier(0);

  for (int t = 0; t < NT; ++t) {
    const int buf = t & 1;
    const int pb = buf ^ 1;
    const char* Lb = lds + buf * 65536;
    const char* Lp = lds + pb * 65536;

    // top: bb0 then bb1 (issue-order pinned for the counted ph1 gate)
    READ_B(bb0, 0, Lb);
    __builtin_amdgcn_sched_barrier(0);
    READ_B(bb1, 1, Lb);
    __builtin_amdgcn_sched_barrier(0);

    // ---- ph1: quadrant (0,0) — needs af0 (prefetched) + bb0 ----
    if (t + 1 < NT) { STAGE_A(t + 1, pb, 2); STAGE_A(t + 1, pb, 3); }
    __builtin_amdgcn_s_barrier();
    asm volatile("s_waitcnt lgkmcnt(4)" ::: "memory");  // af0+bb0 done; bb1 in flight
    __builtin_amdgcn_sched_barrier(0);
    MFMA_Q(0, 0, af0, bb0);
    __builtin_amdgcn_s_barrier();

    // ---- ph2: quadrant (0,1) — needs bb1; issues af1 (overlaps MFMA) ----
    if (t + 1 < NT) { STAGE_B(t + 1, pb, 0); STAGE_B(t + 1, pb, 1); }
    __builtin_amdgcn_s_barrier();
    asm volatile("s_waitcnt lgkmcnt(0)" ::: "memory");  // bb1 done
    __builtin_amdgcn_sched_barrier(0);
    READ_A(af1, 1, Lb);  // 8 reads in flight across ph2 MFMA + ph3 stage/barrier
    MFMA_Q(0, 1, af0, bb1);
    __builtin_amdgcn_s_barrier();

    // ---- ph3: quadrant (1,1) — needs af1; prefetches af0' for t+1 (overlaps MFMA) ----
    // STAGE into buf A-lower: safe — every wave passed ph2's lgkmcnt(0)
    if (t + 2 < NT) { STAGE_A(t + 2, buf, 0); STAGE_A(t + 2, buf, 1); }
    __builtin_amdgcn_s_barrier();
    asm volatile("s_waitcnt lgkmcnt(0)" ::: "memory");  // af1 done
    __builtin_amdgcn_sched_barrier(0);
    if (t + 1 < NT) READ_A(af0, 0, Lp);  // af0' := A(t+1) lower (landed at boundary t-1)
    MFMA_Q(1, 1, af1, bb1);
    __builtin_amdgcn_s_barrier();

    // ---- ph4: quadrant (1,0) — zero LDS reads, zero lgkm gate (af1+bb0 in regs) ----
    // STAGE into buf B-upper (bb1 rows): safe — all waves passed ph3's lgkmcnt(0)
    if (t + 2 < NT) { STAGE_B(t + 2, buf, 2); STAGE_B(t + 2, buf, 3); }
    __builtin_amdgcn_s_barrier();
    MFMA_Q(1, 0, af1, bb0);

    // boundary: counted vmcnt (T4) — t+1 fully landed, t+2's 4 units in flight
    if (t + 2 < NT) {
      asm volatile("s_waitcnt vmcnt(4)" ::: "memory");
    } else {
      asm volatile("s_waitcnt vmcnt(0)" ::: "memory");
    }
    __builtin_amdgcn_s_barrier();
    __builtin_amdgcn_sched_barrier(0);
  }

  // ---- epilogue: C write, optional fused RoPE on 64-col rope strips ----
  const int colbase = bn * 256 + wc * 64;
  const int rbase = bm * 256 + wr * 64 + ((lane >> 4) << 2);
  const bool isrope = rope && ((colbase % 192) == 128);
  if (isrope) {
#pragma unroll
    for (int qm = 0; qm < 2; ++qm)
#pragma unroll
      for (int mf = 0; mf < 4; ++mf)
#pragma unroll
        for (int nf = 0; nf < 2; ++nf) {
          int i_ = nf * 16 + (lane & 15);
#pragma unroll
          for (int r = 0; r < 4; ++r) {
            int trow = rbase + qm * 128 + mf * 16 + r;
            float c1 = cs[trow * 64 + i_], s1 = sn[trow * 64 + i_];
            float c2 = cs[trow * 64 + 32 + i_], s2 = sn[trow * 64 + 32 + i_];
            float a = acc[qm][0][mf][nf][r], b = acc[qm][1][mf][nf][r];
            C[(size_t)trow * ldc + colbase + i_] = a * c1 - b * s1;
            C[(size_t)trow * ldc + colbase + 32 + i_] = b * c2 + a * s2;
          }
        }
  } else {
#pragma unroll
    for (int qm = 0; qm < 2; ++qm)
#pragma unroll
      for (int qn = 0; qn < 2; ++qn)
#pragma unroll
        for (int mf = 0; mf < 4; ++mf)
#pragma unroll
          for (int nf = 0; nf < 2; ++nf)
#pragma unroll
            for (int r = 0; r < 4; ++r) {
              int trow = rbase + qm * 128 + mf * 16 + r;
              C[(size_t)trow * ldc + colbase + qn * 32 + nf * 16 + (lane & 15)] =
                  acc[qm][qn][mf][nf][r];
            }
  }
#undef MFMA_Q
#undef READ_B
#undef READ_A
#undef STAGE_B
#undef STAGE_A
}

// ---- 128x128 bf16 GEMM (m97 structure) for GEMM1+3: A (M,K), B (N,K), C fp32 ----
__global__ __launch_bounds__(256, 2) void gemm128(
    const unsigned short* __restrict__ A, const unsigned short* __restrict__ B,
    float* __restrict__ C, int K, int ldc, int Nvalid) {
  __shared__ __attribute__((aligned(128))) unsigned short As[128 * 32];
  __shared__ __attribute__((aligned(128))) unsigned short Bs[128 * 32];
  const int tid = threadIdx.x;
  const int lane = tid & 63;
  const int wid = tid >> 6;
  const int wr = wid >> 1, wc = wid & 1;
  const int bm = blockIdx.y, bn = blockIdx.x;
  const size_t abase = (size_t)bm * 128 * K;
  const size_t bbase = (size_t)bn * 128 * K;

  f32x4 acc[4][4];
  const f32x4 zero4 = {0.f, 0.f, 0.f, 0.f};
#pragma unroll
  for (int m = 0; m < 4; ++m)
#pragma unroll
    for (int n = 0; n < 4; ++n) acc[m][n] = zero4;

  const int r0 = tid >> 2;
  const int c0 = (tid & 3) * 8;

  for (int k0 = 0; k0 < K; k0 += 32) {
    gload16(A + abase + (size_t)r0 * K + k0 + c0, As + tid * 8);
    gload16(A + abase + (size_t)(r0 + 64) * K + k0 + c0, As + (256 + tid) * 8);
    gload16(B + bbase + (size_t)r0 * K + k0 + c0, Bs + tid * 8);
    gload16(B + bbase + (size_t)(r0 + 64) * K + k0 + c0, Bs + (256 + tid) * 8);
    __syncthreads();
    bf16x8 af[4], bfr[4];
#pragma unroll
    for (int m = 0; m < 4; ++m)
      af[m] = *(const bf16x8*)(As + (wr * 64 + m * 16 + (lane & 15)) * 32 + (lane >> 4) * 8);
#pragma unroll
    for (int n = 0; n < 4; ++n)
      bfr[n] = *(const bf16x8*)(Bs + (wc * 64 + n * 16 + (lane & 15)) * 32 + (lane >> 4) * 8);
#pragma unroll
    for (int m = 0; m < 4; ++m)
#pragma unroll
      for (int n = 0; n < 4; ++n)
        acc[m][n] = __builtin_amdgcn_mfma_f32_16x16x32_bf16(af[m], bfr[n], acc[m][n], 0, 0, 0);
    __syncthreads();
  }

  const int crow0 = bm * 128 + wr * 64 + ((lane >> 4) << 2);
  const int ccol0 = bn * 128 + wc * 64 + (lane & 15);
#pragma unroll
  for (int m = 0; m < 4; ++m) {
#pragma unroll
    for (int n = 0; n < 4; ++n) {
      int col = ccol0 + n * 16;
      if (col < Nvalid) {
#pragma unroll
        for (int r = 0; r < 4; ++r) {
          int row = crow0 + m * 16 + r;
          C[(size_t)row * ldc + col] = acc[m][n][r];
        }
      }
    }
  }
}

// ---- rmsnorm over cq rows (1536), raw stride 2176, out bf16 ----
__global__ void rmsnorm_cq(const float* __restrict__ raw, const float* __restrict__ gamma,
                           unsigned short* __restrict__ out) {
  __shared__ float red[4];
  int t = blockIdx.x, tid = threadIdx.x;
  const float* r = raw + (size_t)t * 2176;
  float v[6];
  float ss = 0.f;
#pragma unroll
  for (int i = 0; i < 6; ++i) {
    v[i] = r[tid + i * 256];
    ss += v[i] * v[i];
  }
#pragma unroll
  for (int o = 32; o > 0; o >>= 1) ss += __shfl_xor(ss, o, 64);
  if ((tid & 63) == 0) red[tid >> 6] = ss;
  __syncthreads();
  ss = red[0] + red[1] + red[2] + red[3];
  float sc = rsqrtf(ss * (1.f / 1536.f) + 1e-6f);
#pragma unroll
  for (int i = 0; i < 6; ++i)
    out[(size_t)t * 1536 + tid + i * 256] = f2bf(v[i] * sc * gamma[tid + i * 256]);
}

// ---- kv epilogue: rmsnorm(kv[:512]) + rope(kv[512:576]) -> out cols 24576..25152 ----
__global__ void kv_epi(const float* __restrict__ raw, const float* __restrict__ gamma,
                       const float* __restrict__ cs, const float* __restrict__ sn,
                       float* __restrict__ out) {
  __shared__ float red[4];
  int t = blockIdx.x, tid = threadIdx.x;
  const float* r = raw + (size_t)t * 2176 + 1536;
  float v0 = r[tid], v1 = r[tid + 256];
  float ss = v0 * v0 + v1 * v1;
#pragma unroll
  for (int o = 32; o > 0; o >>= 1) ss += __shfl_xor(ss, o, 64);
  if ((tid & 63) == 0) red[tid >> 6] = ss;
  __syncthreads();
  ss = red[0] + red[1] + red[2] + red[3];
  float sc = rsqrtf(ss * (1.f / 512.f) + 1e-6f);
  float* orow = out + (size_t)t * OUT_LD + 24576;
  orow[tid] = v0 * sc * gamma[tid];
  orow[tid + 256] = v1 * sc * gamma[tid + 256];
  if (tid < 32) {
    float a = r[512 + tid], b = r[544 + tid];
    orow[512 + tid] = a * cs[t * 64 + tid] - b * sn[t * 64 + tid];
    orow[544 + tid] = b * cs[t * 64 + 32 + tid] + a * sn[t * 64 + 32 + tid];
  }
}

extern "C" void kernel_launch(void* const* d_in, const int* in_sizes, int n_in,
                              void* d_out, int out_size, void* d_ws, size_t ws_size,
                              hipStream_t stream) {
  const float* token_x = (const float*)d_in[0];   // 4096 x 7168
  const float* wq_a = (const float*)d_in[1];      // 7168 x 1536
  const float* wq_b = (const float*)d_in[2];      // 1536 x 24576
  const float* wkv = (const float*)d_in[3];       // 7168 x 576
  const float* rope_cos = (const float*)d_in[4];  // 4096 x 64
  const float* rope_sin = (const float*)d_in[5];
  const float* gamma_cq = (const float*)d_in[6];   // 1536
  const float* gamma_ckv = (const float*)d_in[7];  // 512
  float* out = (float*)d_out;                      // 4096 x 25152

  char* ws = (char*)d_ws;
  unsigned short* txb = (unsigned short*)ws;                          // 4096x7168 bf16
  unsigned short* wqbT = (unsigned short*)(ws + 58720256);            // 24576x1536 bf16
  unsigned short* Bc = (unsigned short*)(ws + 134217728);             // 2176x7168 bf16
  float* raw = (float*)(ws + 165412864);                              // 4096x2176 f32
  unsigned short* cqb = (unsigned short*)(ws + 201064448);            // 4096x1536 bf16

  // 1) conversions
  cvt_bf16<<<28672, 256, 0, stream>>>(token_x, txb);
  transpose_cvt<<<dim3(7168 / 32, 1536 / 32), dim3(32, 8), 0, stream>>>(wq_a, Bc, 7168, 1536, 1536);
  transpose_cvt<<<dim3(7168 / 32, 640 / 32), dim3(32, 8), 0, stream>>>(
      wkv, Bc + (size_t)1536 * 7168, 7168, 576, 640);
  transpose_cvt<<<dim3(1536 / 32, 24576 / 32), dim3(32, 8), 0, stream>>>(wq_b, wqbT, 1536, 24576, 24576);

  // 2) fused GEMM1+GEMM3: raw = token_x @ [wq_a | wkv | 0pad]  (4096 x 2176, K=7168)
  gemm128<<<dim3(17, 32), 256, 0, stream>>>(txb, Bc, raw, 7168, 2176, 2176);

  // 3) epilogues of stage 1
  rmsnorm_cq<<<4096, 256, 0, stream>>>(raw, gamma_cq, cqb);
  kv_epi<<<4096, 256, 0, stream>>>(raw, gamma_ckv, rope_cos, rope_sin, out);

  // 4) GEMM2 (8-phase 256^2, fused rope): q = cq @ wq_b -> out cols [0, 24576), K=1536
  //    grid = 16 Mtiles * 96 Ntiles = 1536 (% 8 == 0 for XCD swizzle)
  gemm256<<<1536, 512, 0, stream>>>(cqb, wqbT, out, 1536, OUT_LD, 16, rope_cos, rope_sin, 1);
}

// Round 7
// 697.632 us; speedup vs baseline: 1.1764x; 1.0022x over previous
//
#include <hip/hip_runtime.h>

// MLA projection: T=4096, H=7168, N_HEADS=128, QK_NOPE=128, QK_ROPE=64, KV_RANK=512
// out row = [q (128*192=24576) | ckv (512) | k_rope (64)] = 25152 fp32

typedef __attribute__((ext_vector_type(8))) __bf16 bf16x8;
typedef __attribute__((ext_vector_type(4))) float f32x4;

#define OUT_LD 25152

__device__ __forceinline__ unsigned short f2bf(float f) {
  union { float f; unsigned u; } v; v.f = f;
  unsigned r = v.u + 0x7FFFu + ((v.u >> 16) & 1u);  // RNE
  return (unsigned short)(r >> 16);
}

__device__ __forceinline__ void gload16(const void* g, void* l) {
  __builtin_amdgcn_global_load_lds(
      (__attribute__((address_space(1))) void*)(void*)g,
      (__attribute__((address_space(3))) void*)l, 16, 0, 0);
}

// ---- fp32 -> bf16 straight conversion (token_x), 4 elems/thread ----
__global__ void cvt_bf16(const float* __restrict__ in, unsigned short* __restrict__ out) {
  size_t i = (size_t)blockIdx.x * 256 + threadIdx.x;
  float4 f = ((const float4*)in)[i];
  ushort4 o;
  o.x = f2bf(f.x); o.y = f2bf(f.y); o.z = f2bf(f.z); o.w = f2bf(f.w);
  ((ushort4*)out)[i] = o;
}

// ---- fp32 (K x N) -> bf16 (Npad x K) transpose+convert, zero pad rows >= N ----
__global__ void transpose_cvt(const float* __restrict__ in, unsigned short* __restrict__ out,
                              int K, int N, int Npad) {
  __shared__ float tile[32][33];
  int k0 = blockIdx.x * 32, n0 = blockIdx.y * 32;
  int tx = threadIdx.x, ty = threadIdx.y;  // 32 x 8
#pragma unroll
  for (int i = 0; i < 4; ++i) {
    int k = k0 + ty + i * 8;
    int n = n0 + tx;
    tile[ty + i * 8][tx] = (n < N) ? in[(size_t)k * N + n] : 0.f;
  }
  __syncthreads();
#pragma unroll
  for (int i = 0; i < 4; ++i) {
    int n = n0 + ty + i * 8;
    int k = k0 + tx;
    if (n < Npad) out[(size_t)n * K + k] = f2bf(tile[tx][ty + i * 8]);
  }
}

// ======================================================================
// 256x256 GEMM, round-7: ONE barrier + ONE vmcnt per K-tile. Stage ALL of
// tile t+1 into the other buffer at iter top (whole-body latency budget ->
// boundary vmcnt(0) nearly free); all 24 ds_reads issued in pinned order
// (af0,bb0 | bb1 | af1) with counted lgkmcnt(12/8/0) gates so the LDS port
// drains UNDER the MFMA bursts. Buffer safety: reads<-buf, stages->pb
// (disjoint), single end-of-iter barrier. T1 XCD swizzle, T2 3-bit XOR
// swizzle (0 conflicts), T5 setprio. A (M,K) k-contig, B (N,K) k-contig.
// 512 threads = 8 waves (2 M x 4 N). BK=64. LDS 128 KiB (2 dbuf).
// ======================================================================
__global__ __launch_bounds__(512, 2) void gemm256(
    const unsigned short* __restrict__ A, const unsigned short* __restrict__ B,
    float* __restrict__ C, int K, int ldc, int Mtiles,
    const float* __restrict__ cs, const float* __restrict__ sn, int rope) {
  __shared__ __attribute__((aligned(128))) char lds[131072];
  const int tid = threadIdx.x;
  const int lane = tid & 63;
  const int wr = (tid >> 6) >> 2;  // 0..1
  const int wc = (tid >> 6) & 3;   // 0..3
  const int NT = K >> 6;

  // T1: XCD-aware block swizzle (grid % 8 == 0 by launch)
  const int nwg = gridDim.x;
  const int per = nwg >> 3;
  const int bid = blockIdx.x;
  const int swz = (bid & 7) * per + (bid >> 3);
  const int bm = swz % Mtiles, bn = swz / Mtiles;

  // staging geometry: thread covers 16 B at linear LDS byte tid*16;
  // ldsrow = tid>>3, chunk = tid&7; source col pre-swizzled (rule #21)
  const int strow = tid >> 3;
  const int stcolb = (((tid & 7) ^ ((tid >> 3) & 7)) << 4);
  const size_t abase = (size_t)(bm * 256) * K;
  const size_t bbase = (size_t)(bn * 256) * K;

  f32x4 acc[2][2][4][2];
  const f32x4 z4 = {0.f, 0.f, 0.f, 0.f};
#pragma unroll
  for (int a = 0; a < 2; ++a)
#pragma unroll
    for (int b = 0; b < 2; ++b)
#pragma unroll
      for (int c = 0; c < 4; ++c)
#pragma unroll
        for (int d = 0; d < 2; ++d) acc[a][b][c][d] = z4;

// A LDS: region buf*65536 + 0,     rows 0..255 natural (row = m), 128 B/row
// B LDS: region buf*65536 + 32768, rows permuted: ldsrow(n) = ((n>>5)&1)*128 + ((n>>6)&3)*32 + (n&31)
#define STAGE_A(kt, bsel, u)                                                          \
  do {                                                                                \
    int row_ = (u) * 64 + strow;                                                      \
    gload16((const char*)(A + abase + (size_t)row_ * K + (size_t)(kt) * 64) + stcolb, \
            lds + (bsel) * 65536 + (u) * 8192 + tid * 16);                            \
  } while (0)
#define STAGE_B(kt, bsel, u)                                                          \
  do {                                                                                \
    int lrow_ = (u) * 64 + strow;                                                     \
    int n_ = ((lrow_ >> 5) & 3) * 64 + ((lrow_ >> 7) & 1) * 32 + (lrow_ & 31);        \
    gload16((const char*)(B + bbase + (size_t)n_ * K + (size_t)(kt) * 64) + stcolb,   \
            lds + (bsel) * 65536 + 32768 + (u) * 8192 + tid * 16);                    \
  } while (0)

#define READ_A(dst, QM, LBASE)                                              \
  do {                                                                      \
    _Pragma("unroll") for (int mf = 0; mf < 4; ++mf)                        \
        _Pragma("unroll") for (int ks = 0; ks < 2; ++ks) {                  \
      int row_ = (QM) * 128 + wr * 64 + mf * 16 + (lane & 15);              \
      int in_ = (ks * 64 + ((lane >> 4) << 4)) ^ ((row_ & 7) << 4);         \
      dst[mf][ks] = *(const bf16x8*)((LBASE) + row_ * 128 + in_);           \
    }                                                                       \
  } while (0)
#define READ_B(dst, QN, LBASE)                                              \
  do {                                                                      \
    _Pragma("unroll") for (int nf = 0; nf < 2; ++nf)                        \
        _Pragma("unroll") for (int ks = 0; ks < 2; ++ks) {                  \
      int c_ = wc * 64 + (QN) * 32 + nf * 16 + (lane & 15);                 \
      int rr_ = ((c_ >> 5) & 1) * 128 + ((c_ >> 6) & 3) * 32 + (c_ & 31);   \
      int in_ = (ks * 64 + ((lane >> 4) << 4)) ^ ((rr_ & 7) << 4);          \
      dst[nf][ks] = *(const bf16x8*)((LBASE) + 32768 + rr_ * 128 + in_);    \
    }                                                                       \
  } while (0)
#define MFMA_Q(QM, QN, AF, BB)                                              \
  do {                                                                      \
    __builtin_amdgcn_s_setprio(1);                                          \
    _Pragma("unroll") for (int mf = 0; mf < 4; ++mf)                        \
        _Pragma("unroll") for (int nf = 0; nf < 2; ++nf)                    \
            _Pragma("unroll") for (int ks = 0; ks < 2; ++ks)                \
                acc[QM][QN][mf][nf] = __builtin_amdgcn_mfma_f32_16x16x32_bf16( \
                    AF[mf][ks], BB[nf][ks], acc[QM][QN][mf][nf], 0, 0, 0);  \
    __builtin_amdgcn_s_setprio(0);                                          \
  } while (0)

  // ---- prologue: stage tile0 -> buf0, drain, barrier ----
  STAGE_A(0, 0, 0); STAGE_A(0, 0, 1); STAGE_A(0, 0, 2); STAGE_A(0, 0, 3);
  STAGE_B(0, 0, 0); STAGE_B(0, 0, 1); STAGE_B(0, 0, 2); STAGE_B(0, 0, 3);
  asm volatile("s_waitcnt vmcnt(0)" ::: "memory");
  __builtin_amdgcn_s_barrier();
  __builtin_amdgcn_sched_barrier(0);

  bf16x8 af0[4][2], af1[4][2], bb0[2][2], bb1[2][2];

  for (int t = 0; t < NT; ++t) {
    const int buf = t & 1;
    const int pb = buf ^ 1;
    const char* Lb = lds + buf * 65536;

    // stage ALL of tile t+1 into pb — a full iteration of latency budget
    if (t + 1 < NT) {
      STAGE_A(t + 1, pb, 0); STAGE_A(t + 1, pb, 1);
      STAGE_A(t + 1, pb, 2); STAGE_A(t + 1, pb, 3);
      STAGE_B(t + 1, pb, 0); STAGE_B(t + 1, pb, 1);
      STAGE_B(t + 1, pb, 2); STAGE_B(t + 1, pb, 3);
    }
    __builtin_amdgcn_sched_barrier(0);

    // issue all 24 ds_reads in pinned gate order: af0+bb0 (12) | bb1 (4) | af1 (8)
    READ_A(af0, 0, Lb);
    READ_B(bb0, 0, Lb);
    __builtin_amdgcn_sched_barrier(0);
    READ_B(bb1, 1, Lb);
    __builtin_amdgcn_sched_barrier(0);
    READ_A(af1, 1, Lb);
    __builtin_amdgcn_sched_barrier(0);

    // Q(0,0): af0+bb0 done when <=12 outstanding (bb1+af1)
    asm volatile("s_waitcnt lgkmcnt(12)" ::: "memory");
    __builtin_amdgcn_sched_barrier(0);
    MFMA_Q(0, 0, af0, bb0);

    // Q(0,1): bb1 done when <=8 outstanding (af1)
    asm volatile("s_waitcnt lgkmcnt(8)" ::: "memory");
    __builtin_amdgcn_sched_barrier(0);
    MFMA_Q(0, 1, af0, bb1);

    // Q(1,1) + Q(1,0): af1 done
    asm volatile("s_waitcnt lgkmcnt(0)" ::: "memory");
    __builtin_amdgcn_sched_barrier(0);
    MFMA_Q(1, 1, af1, bb1);
    MFMA_Q(1, 0, af1, bb0);

    // boundary: t+1 loads landed (issued ~3000 cyc ago) + all waves done with buf
    asm volatile("s_waitcnt vmcnt(0)" ::: "memory");
    __builtin_amdgcn_s_barrier();
    __builtin_amdgcn_sched_barrier(0);
  }

  // ---- epilogue: C write, optional fused RoPE on 64-col rope strips ----
  const int colbase = bn * 256 + wc * 64;
  const int rbase = bm * 256 + wr * 64 + ((lane >> 4) << 2);
  const bool isrope = rope && ((colbase % 192) == 128);
  if (isrope) {
#pragma unroll
    for (int qm = 0; qm < 2; ++qm)
#pragma unroll
      for (int mf = 0; mf < 4; ++mf)
#pragma unroll
        for (int nf = 0; nf < 2; ++nf) {
          int i_ = nf * 16 + (lane & 15);
#pragma unroll
          for (int r = 0; r < 4; ++r) {
            int trow = rbase + qm * 128 + mf * 16 + r;
            float c1 = cs[trow * 64 + i_], s1 = sn[trow * 64 + i_];
            float c2 = cs[trow * 64 + 32 + i_], s2 = sn[trow * 64 + 32 + i_];
            float a = acc[qm][0][mf][nf][r], b = acc[qm][1][mf][nf][r];
            C[(size_t)trow * ldc + colbase + i_] = a * c1 - b * s1;
            C[(size_t)trow * ldc + colbase + 32 + i_] = b * c2 + a * s2;
          }
        }
  } else {
#pragma unroll
    for (int qm = 0; qm < 2; ++qm)
#pragma unroll
      for (int qn = 0; qn < 2; ++qn)
#pragma unroll
        for (int mf = 0; mf < 4; ++mf)
#pragma unroll
          for (int nf = 0; nf < 2; ++nf)
#pragma unroll
            for (int r = 0; r < 4; ++r) {
              int trow = rbase + qm * 128 + mf * 16 + r;
              C[(size_t)trow * ldc + colbase + qn * 32 + nf * 16 + (lane & 15)] =
                  acc[qm][qn][mf][nf][r];
            }
  }
#undef MFMA_Q
#undef READ_B
#undef READ_A
#undef STAGE_B
#undef STAGE_A
}

// ---- 128x128 bf16 GEMM (m97 structure) for GEMM1+3: A (M,K), B (N,K), C fp32 ----
__global__ __launch_bounds__(256, 2) void gemm128(
    const unsigned short* __restrict__ A, const unsigned short* __restrict__ B,
    float* __restrict__ C, int K, int ldc, int Nvalid) {
  __shared__ __attribute__((aligned(128))) unsigned short As[128 * 32];
  __shared__ __attribute__((aligned(128))) unsigned short Bs[128 * 32];
  const int tid = threadIdx.x;
  const int lane = tid & 63;
  const int wid = tid >> 6;
  const int wr = wid >> 1, wc = wid & 1;
  const int bm = blockIdx.y, bn = blockIdx.x;
  const size_t abase = (size_t)bm * 128 * K;
  const size_t bbase = (size_t)bn * 128 * K;

  f32x4 acc[4][4];
  const f32x4 zero4 = {0.f, 0.f, 0.f, 0.f};
#pragma unroll
  for (int m = 0; m < 4; ++m)
#pragma unroll
    for (int n = 0; n < 4; ++n) acc[m][n] = zero4;

  const int r0 = tid >> 2;
  const int c0 = (tid & 3) * 8;

  for (int k0 = 0; k0 < K; k0 += 32) {
    gload16(A + abase + (size_t)r0 * K + k0 + c0, As + tid * 8);
    gload16(A + abase + (size_t)(r0 + 64) * K + k0 + c0, As + (256 + tid) * 8);
    gload16(B + bbase + (size_t)r0 * K + k0 + c0, Bs + tid * 8);
    gload16(B + bbase + (size_t)(r0 + 64) * K + k0 + c0, Bs + (256 + tid) * 8);
    __syncthreads();
    bf16x8 af[4], bfr[4];
#pragma unroll
    for (int m = 0; m < 4; ++m)
      af[m] = *(const bf16x8*)(As + (wr * 64 + m * 16 + (lane & 15)) * 32 + (lane >> 4) * 8);
#pragma unroll
    for (int n = 0; n < 4; ++n)
      bfr[n] = *(const bf16x8*)(Bs + (wc * 64 + n * 16 + (lane & 15)) * 32 + (lane >> 4) * 8);
#pragma unroll
    for (int m = 0; m < 4; ++m)
#pragma unroll
      for (int n = 0; n < 4; ++n)
        acc[m][n] = __builtin_amdgcn_mfma_f32_16x16x32_bf16(af[m], bfr[n], acc[m][n], 0, 0, 0);
    __syncthreads();
  }

  const int crow0 = bm * 128 + wr * 64 + ((lane >> 4) << 2);
  const int ccol0 = bn * 128 + wc * 64 + (lane & 15);
#pragma unroll
  for (int m = 0; m < 4; ++m) {
#pragma unroll
    for (int n = 0; n < 4; ++n) {
      int col = ccol0 + n * 16;
      if (col < Nvalid) {
#pragma unroll
        for (int r = 0; r < 4; ++r) {
          int row = crow0 + m * 16 + r;
          C[(size_t)row * ldc + col] = acc[m][n][r];
        }
      }
    }
  }
}

// ---- rmsnorm over cq rows (1536), raw stride 2176, out bf16 ----
__global__ void rmsnorm_cq(const float* __restrict__ raw, const float* __restrict__ gamma,
                           unsigned short* __restrict__ out) {
  __shared__ float red[4];
  int t = blockIdx.x, tid = threadIdx.x;
  const float* r = raw + (size_t)t * 2176;
  float v[6];
  float ss = 0.f;
#pragma unroll
  for (int i = 0; i < 6; ++i) {
    v[i] = r[tid + i * 256];
    ss += v[i] * v[i];
  }
#pragma unroll
  for (int o = 32; o > 0; o >>= 1) ss += __shfl_xor(ss, o, 64);
  if ((tid & 63) == 0) red[tid >> 6] = ss;
  __syncthreads();
  ss = red[0] + red[1] + red[2] + red[3];
  float sc = rsqrtf(ss * (1.f / 1536.f) + 1e-6f);
#pragma unroll
  for (int i = 0; i < 6; ++i)
    out[(size_t)t * 1536 + tid + i * 256] = f2bf(v[i] * sc * gamma[tid + i * 256]);
}

// ---- kv epilogue: rmsnorm(kv[:512]) + rope(kv[512:576]) -> out cols 24576..25152 ----
__global__ void kv_epi(const float* __restrict__ raw, const float* __restrict__ gamma,
                       const float* __restrict__ cs, const float* __restrict__ sn,
                       float* __restrict__ out) {
  __shared__ float red[4];
  int t = blockIdx.x, tid = threadIdx.x;
  const float* r = raw + (size_t)t * 2176 + 1536;
  float v0 = r[tid], v1 = r[tid + 256];
  float ss = v0 * v0 + v1 * v1;
#pragma unroll
  for (int o = 32; o > 0; o >>= 1) ss += __shfl_xor(ss, o, 64);
  if ((tid & 63) == 0) red[tid >> 6] = ss;
  __syncthreads();
  ss = red[0] + red[1] + red[2] + red[3];
  float sc = rsqrtf(ss * (1.f / 512.f) + 1e-6f);
  float* orow = out + (size_t)t * OUT_LD + 24576;
  orow[tid] = v0 * sc * gamma[tid];
  orow[tid + 256] = v1 * sc * gamma[tid + 256];
  if (tid < 32) {
    float a = r[512 + tid], b = r[544 + tid];
    orow[512 + tid] = a * cs[t * 64 + tid] - b * sn[t * 64 + tid];
    orow[544 + tid] = b * cs[t * 64 + 32 + tid] + a * sn[t * 64 + 32 + tid];
  }
}

extern "C" void kernel_launch(void* const* d_in, const int* in_sizes, int n_in,
                              void* d_out, int out_size, void* d_ws, size_t ws_size,
                              hipStream_t stream) {
  const float* token_x = (const float*)d_in[0];   // 4096 x 7168
  const float* wq_a = (const float*)d_in[1];      // 7168 x 1536
  const float* wq_b = (const float*)d_in[2];      // 1536 x 24576
  const float* wkv = (const float*)d_in[3];       // 7168 x 576
  const float* rope_cos = (const float*)d_in[4];  // 4096 x 64
  const float* rope_sin = (const float*)d_in[5];
  const float* gamma_cq = (const float*)d_in[6];   // 1536
  const float* gamma_ckv = (const float*)d_in[7];  // 512
  float* out = (float*)d_out;                      // 4096 x 25152

  char* ws = (char*)d_ws;
  unsigned short* txb = (unsigned short*)ws;                          // 4096x7168 bf16
  unsigned short* wqbT = (unsigned short*)(ws + 58720256);            // 24576x1536 bf16
  unsigned short* Bc = (unsigned short*)(ws + 134217728);             // 2176x7168 bf16
  float* raw = (float*)(ws + 165412864);                              // 4096x2176 f32
  unsigned short* cqb = (unsigned short*)(ws + 201064448);            // 4096x1536 bf16

  // 1) conversions
  cvt_bf16<<<28672, 256, 0, stream>>>(token_x, txb);
  transpose_cvt<<<dim3(7168 / 32, 1536 / 32), dim3(32, 8), 0, stream>>>(wq_a, Bc, 7168, 1536, 1536);
  transpose_cvt<<<dim3(7168 / 32, 640 / 32), dim3(32, 8), 0, stream>>>(
      wkv, Bc + (size_t)1536 * 7168, 7168, 576, 640);
  transpose_cvt<<<dim3(1536 / 32, 24576 / 32), dim3(32, 8), 0, stream>>>(wq_b, wqbT, 1536, 24576, 24576);

  // 2) fused GEMM1+GEMM3: raw = token_x @ [wq_a | wkv | 0pad]  (4096 x 2176, K=7168)
  gemm128<<<dim3(17, 32), 256, 0, stream>>>(txb, Bc, raw, 7168, 2176, 2176);

  // 3) epilogues of stage 1
  rmsnorm_cq<<<4096, 256, 0, stream>>>(raw, gamma_cq, cqb);
  kv_epi<<<4096, 256, 0, stream>>>(raw, gamma_ckv, rope_cos, rope_sin, out);

  // 4) GEMM2 (1-barrier/K-tile 256^2, fused rope): q = cq @ wq_b -> out cols [0, 24576), K=1536
  //    grid = 16 Mtiles * 96 Ntiles = 1536 (% 8 == 0 for XCD swizzle)
  gemm256<<<1536, 512, 0, stream>>>(cqb, wqbT, out, 1536, OUT_LD, 16, rope_cos, rope_sin, 1);
}

// Round 8
// 684.081 us; speedup vs baseline: 1.1997x; 1.0198x over previous
//
#include <hip/hip_runtime.h>

// MLA projection: T=4096, H=7168, N_HEADS=128, QK_NOPE=128, QK_ROPE=64, KV_RANK=512
// out row = [q (128*192=24576) | ckv (512) | k_rope (64)] = 25152 fp32

typedef __attribute__((ext_vector_type(8))) __bf16 bf16x8;
typedef __attribute__((ext_vector_type(4))) float f32x4;

#define OUT_LD 25152

__device__ __forceinline__ unsigned short f2bf(float f) {
  union { float f; unsigned u; } v; v.f = f;
  unsigned r = v.u + 0x7FFFu + ((v.u >> 16) & 1u);  // RNE
  return (unsigned short)(r >> 16);
}

__device__ __forceinline__ void gload16(const void* g, void* l) {
  __builtin_amdgcn_global_load_lds(
      (__attribute__((address_space(1))) void*)(void*)g,
      (__attribute__((address_space(3))) void*)l, 16, 0, 0);
}

// ---- fp32 -> bf16 straight conversion (token_x), 4 elems/thread ----
__global__ void cvt_bf16(const float* __restrict__ in, unsigned short* __restrict__ out) {
  size_t i = (size_t)blockIdx.x * 256 + threadIdx.x;
  float4 f = ((const float4*)in)[i];
  ushort4 o;
  o.x = f2bf(f.x); o.y = f2bf(f.y); o.z = f2bf(f.z); o.w = f2bf(f.w);
  ((ushort4*)out)[i] = o;
}

// ---- fp32 (K x N) -> bf16 (Npad x K) transpose+convert, zero pad rows >= N ----
__global__ void transpose_cvt(const float* __restrict__ in, unsigned short* __restrict__ out,
                              int K, int N, int Npad) {
  __shared__ float tile[32][33];
  int k0 = blockIdx.x * 32, n0 = blockIdx.y * 32;
  int tx = threadIdx.x, ty = threadIdx.y;  // 32 x 8
#pragma unroll
  for (int i = 0; i < 4; ++i) {
    int k = k0 + ty + i * 8;
    int n = n0 + tx;
    tile[ty + i * 8][tx] = (n < N) ? in[(size_t)k * N + n] : 0.f;
  }
  __syncthreads();
#pragma unroll
  for (int i = 0; i < 4; ++i) {
    int n = n0 + ty + i * 8;
    int k = k0 + tx;
    if (n < Npad) out[(size_t)n * K + k] = f2bf(tile[tx][ty + i * 8]);
  }
}

// ======================================================================
// 256x256 GEMM, round-8: DE-PINNED. One __syncthreads() per K-tile (its
// vmcnt(0)+lgkmcnt(0)+barrier is the boundary); no manual waitcnt, no
// sched_barrier — compiler owns ds_read/MFMA/VALU interleave (m97/m141
// evidence: pinning defeats the scheduler). Stage all of t+1 at iter top
// (full-iter latency budget). T1 XCD swizzle, T2 3-bit XOR swizzle
// (0 conflicts), T5 setprio around the MFMA region.
// A (M,K) k-contig, B (N,K) k-contig, C fp32.
// 512 threads = 8 waves (2 M x 4 N). BK=64. LDS 128 KiB (2 dbuf).
// ======================================================================
__global__ __launch_bounds__(512, 2) void gemm256(
    const unsigned short* __restrict__ A, const unsigned short* __restrict__ B,
    float* __restrict__ C, int K, int ldc, int Mtiles,
    const float* __restrict__ cs, const float* __restrict__ sn, int rope) {
  __shared__ __attribute__((aligned(128))) char lds[131072];
  const int tid = threadIdx.x;
  const int lane = tid & 63;
  const int wr = (tid >> 6) >> 2;  // 0..1
  const int wc = (tid >> 6) & 3;   // 0..3
  const int NT = K >> 6;

  // T1: XCD-aware block swizzle (grid % 8 == 0 by launch)
  const int nwg = gridDim.x;
  const int per = nwg >> 3;
  const int bid = blockIdx.x;
  const int swz = (bid & 7) * per + (bid >> 3);
  const int bm = swz % Mtiles, bn = swz / Mtiles;

  // staging geometry: thread covers 16 B at linear LDS byte tid*16;
  // ldsrow = tid>>3, chunk = tid&7; source col pre-swizzled (rule #21)
  const int strow = tid >> 3;
  const int stcolb = (((tid & 7) ^ ((tid >> 3) & 7)) << 4);
  const size_t abase = (size_t)(bm * 256) * K;
  const size_t bbase = (size_t)(bn * 256) * K;

  f32x4 acc[2][2][4][2];
  const f32x4 z4 = {0.f, 0.f, 0.f, 0.f};
#pragma unroll
  for (int a = 0; a < 2; ++a)
#pragma unroll
    for (int b = 0; b < 2; ++b)
#pragma unroll
      for (int c = 0; c < 4; ++c)
#pragma unroll
        for (int d = 0; d < 2; ++d) acc[a][b][c][d] = z4;

// A LDS: region buf*65536 + 0,     rows 0..255 natural (row = m), 128 B/row
// B LDS: region buf*65536 + 32768, rows permuted: ldsrow(n) = ((n>>5)&1)*128 + ((n>>6)&3)*32 + (n&31)
#define STAGE_A(kt, bsel, u)                                                          \
  do {                                                                                \
    int row_ = (u) * 64 + strow;                                                      \
    gload16((const char*)(A + abase + (size_t)row_ * K + (size_t)(kt) * 64) + stcolb, \
            lds + (bsel) * 65536 + (u) * 8192 + tid * 16);                            \
  } while (0)
#define STAGE_B(kt, bsel, u)                                                          \
  do {                                                                                \
    int lrow_ = (u) * 64 + strow;                                                     \
    int n_ = ((lrow_ >> 5) & 3) * 64 + ((lrow_ >> 7) & 1) * 32 + (lrow_ & 31);        \
    gload16((const char*)(B + bbase + (size_t)n_ * K + (size_t)(kt) * 64) + stcolb,   \
            lds + (bsel) * 65536 + 32768 + (u) * 8192 + tid * 16);                    \
  } while (0)

#define READ_A(dst, QM, LBASE)                                              \
  do {                                                                      \
    _Pragma("unroll") for (int mf = 0; mf < 4; ++mf)                        \
        _Pragma("unroll") for (int ks = 0; ks < 2; ++ks) {                  \
      int row_ = (QM) * 128 + wr * 64 + mf * 16 + (lane & 15);              \
      int in_ = (ks * 64 + ((lane >> 4) << 4)) ^ ((row_ & 7) << 4);         \
      dst[mf][ks] = *(const bf16x8*)((LBASE) + row_ * 128 + in_);           \
    }                                                                       \
  } while (0)
#define READ_B(dst, QN, LBASE)                                              \
  do {                                                                      \
    _Pragma("unroll") for (int nf = 0; nf < 2; ++nf)                        \
        _Pragma("unroll") for (int ks = 0; ks < 2; ++ks) {                  \
      int c_ = wc * 64 + (QN) * 32 + nf * 16 + (lane & 15);                 \
      int rr_ = ((c_ >> 5) & 1) * 128 + ((c_ >> 6) & 3) * 32 + (c_ & 31);   \
      int in_ = (ks * 64 + ((lane >> 4) << 4)) ^ ((rr_ & 7) << 4);          \
      dst[nf][ks] = *(const bf16x8*)((LBASE) + 32768 + rr_ * 128 + in_);    \
    }                                                                       \
  } while (0)
#define MFMA_Q(QM, QN, AF, BB)                                              \
  do {                                                                      \
    _Pragma("unroll") for (int mf = 0; mf < 4; ++mf)                        \
        _Pragma("unroll") for (int nf = 0; nf < 2; ++nf)                    \
            _Pragma("unroll") for (int ks = 0; ks < 2; ++ks)                \
                acc[QM][QN][mf][nf] = __builtin_amdgcn_mfma_f32_16x16x32_bf16( \
                    AF[mf][ks], BB[nf][ks], acc[QM][QN][mf][nf], 0, 0, 0);  \
  } while (0)

  // ---- prologue: stage tile0 -> buf0 ----
  STAGE_A(0, 0, 0); STAGE_A(0, 0, 1); STAGE_A(0, 0, 2); STAGE_A(0, 0, 3);
  STAGE_B(0, 0, 0); STAGE_B(0, 0, 1); STAGE_B(0, 0, 2); STAGE_B(0, 0, 3);
  __syncthreads();  // vmcnt(0) + barrier

  bf16x8 af0[4][2], af1[4][2], bb0[2][2], bb1[2][2];

  for (int t = 0; t < NT; ++t) {
    const int buf = t & 1;
    const int pb = buf ^ 1;
    const char* Lb = lds + buf * 65536;

    // stage ALL of tile t+1 into pb — a full iteration of latency budget
    if (t + 1 < NT) {
      STAGE_A(t + 1, pb, 0); STAGE_A(t + 1, pb, 1);
      STAGE_A(t + 1, pb, 2); STAGE_A(t + 1, pb, 3);
      STAGE_B(t + 1, pb, 0); STAGE_B(t + 1, pb, 1);
      STAGE_B(t + 1, pb, 2); STAGE_B(t + 1, pb, 3);
    }

    // all 24 ds_reads — compiler schedules/interleaves with MFMA + addr VALU
    READ_A(af0, 0, Lb);
    READ_B(bb0, 0, Lb);
    READ_B(bb1, 1, Lb);
    READ_A(af1, 1, Lb);

    __builtin_amdgcn_s_setprio(1);
    MFMA_Q(0, 0, af0, bb0);
    MFMA_Q(0, 1, af0, bb1);
    MFMA_Q(1, 1, af1, bb1);
    MFMA_Q(1, 0, af1, bb0);
    __builtin_amdgcn_s_setprio(0);

    // boundary: drains vmcnt(0) (t+1 staged) + barrier in one op
    __syncthreads();
  }

  // ---- epilogue: C write, optional fused RoPE on 64-col rope strips ----
  const int colbase = bn * 256 + wc * 64;
  const int rbase = bm * 256 + wr * 64 + ((lane >> 4) << 2);
  const bool isrope = rope && ((colbase % 192) == 128);
  if (isrope) {
#pragma unroll
    for (int qm = 0; qm < 2; ++qm)
#pragma unroll
      for (int mf = 0; mf < 4; ++mf)
#pragma unroll
        for (int nf = 0; nf < 2; ++nf) {
          int i_ = nf * 16 + (lane & 15);
#pragma unroll
          for (int r = 0; r < 4; ++r) {
            int trow = rbase + qm * 128 + mf * 16 + r;
            float c1 = cs[trow * 64 + i_], s1 = sn[trow * 64 + i_];
            float c2 = cs[trow * 64 + 32 + i_], s2 = sn[trow * 64 + 32 + i_];
            float a = acc[qm][0][mf][nf][r], b = acc[qm][1][mf][nf][r];
            C[(size_t)trow * ldc + colbase + i_] = a * c1 - b * s1;
            C[(size_t)trow * ldc + colbase + 32 + i_] = b * c2 + a * s2;
          }
        }
  } else {
#pragma unroll
    for (int qm = 0; qm < 2; ++qm)
#pragma unroll
      for (int qn = 0; qn < 2; ++qn)
#pragma unroll
        for (int mf = 0; mf < 4; ++mf)
#pragma unroll
          for (int nf = 0; nf < 2; ++nf)
#pragma unroll
            for (int r = 0; r < 4; ++r) {
              int trow = rbase + qm * 128 + mf * 16 + r;
              C[(size_t)trow * ldc + colbase + qn * 32 + nf * 16 + (lane & 15)] =
                  acc[qm][qn][mf][nf][r];
            }
  }
#undef MFMA_Q
#undef READ_B
#undef READ_A
#undef STAGE_B
#undef STAGE_A
}

// ---- 128x128 bf16 GEMM (m97 structure) for GEMM1+3: A (M,K), B (N,K), C fp32 ----
__global__ __launch_bounds__(256, 2) void gemm128(
    const unsigned short* __restrict__ A, const unsigned short* __restrict__ B,
    float* __restrict__ C, int K, int ldc, int Nvalid) {
  __shared__ __attribute__((aligned(128))) unsigned short As[128 * 32];
  __shared__ __attribute__((aligned(128))) unsigned short Bs[128 * 32];
  const int tid = threadIdx.x;
  const int lane = tid & 63;
  const int wid = tid >> 6;
  const int wr = wid >> 1, wc = wid & 1;
  const int bm = blockIdx.y, bn = blockIdx.x;
  const size_t abase = (size_t)bm * 128 * K;
  const size_t bbase = (size_t)bn * 128 * K;

  f32x4 acc[4][4];
  const f32x4 zero4 = {0.f, 0.f, 0.f, 0.f};
#pragma unroll
  for (int m = 0; m < 4; ++m)
#pragma unroll
    for (int n = 0; n < 4; ++n) acc[m][n] = zero4;

  const int r0 = tid >> 2;
  const int c0 = (tid & 3) * 8;

  for (int k0 = 0; k0 < K; k0 += 32) {
    gload16(A + abase + (size_t)r0 * K + k0 + c0, As + tid * 8);
    gload16(A + abase + (size_t)(r0 + 64) * K + k0 + c0, As + (256 + tid) * 8);
    gload16(B + bbase + (size_t)r0 * K + k0 + c0, Bs + tid * 8);
    gload16(B + bbase + (size_t)(r0 + 64) * K + k0 + c0, Bs + (256 + tid) * 8);
    __syncthreads();
    bf16x8 af[4], bfr[4];
#pragma unroll
    for (int m = 0; m < 4; ++m)
      af[m] = *(const bf16x8*)(As + (wr * 64 + m * 16 + (lane & 15)) * 32 + (lane >> 4) * 8);
#pragma unroll
    for (int n = 0; n < 4; ++n)
      bfr[n] = *(const bf16x8*)(Bs + (wc * 64 + n * 16 + (lane & 15)) * 32 + (lane >> 4) * 8);
#pragma unroll
    for (int m = 0; m < 4; ++m)
#pragma unroll
      for (int n = 0; n < 4; ++n)
        acc[m][n] = __builtin_amdgcn_mfma_f32_16x16x32_bf16(af[m], bfr[n], acc[m][n], 0, 0, 0);
    __syncthreads();
  }

  const int crow0 = bm * 128 + wr * 64 + ((lane >> 4) << 2);
  const int ccol0 = bn * 128 + wc * 64 + (lane & 15);
#pragma unroll
  for (int m = 0; m < 4; ++m) {
#pragma unroll
    for (int n = 0; n < 4; ++n) {
      int col = ccol0 + n * 16;
      if (col < Nvalid) {
#pragma unroll
        for (int r = 0; r < 4; ++r) {
          int row = crow0 + m * 16 + r;
          C[(size_t)row * ldc + col] = acc[m][n][r];
        }
      }
    }
  }
}

// ---- merged stage-1 epilogue: rmsnorm(cq)->bf16, rmsnorm(ckv)+rope(k_rope)->out ----
__global__ void epi1(const float* __restrict__ raw, const float* __restrict__ gcq,
                     const float* __restrict__ gckv, const float* __restrict__ cs,
                     const float* __restrict__ sn, unsigned short* __restrict__ cqb,
                     float* __restrict__ out) {
  __shared__ float red[4];
  int t = blockIdx.x, tid = threadIdx.x;
  const float* r = raw + (size_t)t * 2176;
  // --- cq rmsnorm (cols 0..1535) ---
  float v[6];
  float ss = 0.f;
#pragma unroll
  for (int i = 0; i < 6; ++i) {
    v[i] = r[tid + i * 256];
    ss += v[i] * v[i];
  }
#pragma unroll
  for (int o = 32; o > 0; o >>= 1) ss += __shfl_xor(ss, o, 64);
  if ((tid & 63) == 0) red[tid >> 6] = ss;
  __syncthreads();
  ss = red[0] + red[1] + red[2] + red[3];
  float sc = rsqrtf(ss * (1.f / 1536.f) + 1e-6f);
#pragma unroll
  for (int i = 0; i < 6; ++i)
    cqb[(size_t)t * 1536 + tid + i * 256] = f2bf(v[i] * sc * gcq[tid + i * 256]);
  // --- kv: rmsnorm cols 1536..2047, rope cols 2048..2111 ---
  float v0 = r[1536 + tid], v1 = r[1792 + tid];
  float s2 = v0 * v0 + v1 * v1;
#pragma unroll
  for (int o = 32; o > 0; o >>= 1) s2 += __shfl_xor(s2, o, 64);
  __syncthreads();  // red[] reuse
  if ((tid & 63) == 0) red[tid >> 6] = s2;
  __syncthreads();
  s2 = red[0] + red[1] + red[2] + red[3];
  float sck = rsqrtf(s2 * (1.f / 512.f) + 1e-6f);
  float* orow = out + (size_t)t * OUT_LD + 24576;
  orow[tid] = v0 * sck * gckv[tid];
  orow[tid + 256] = v1 * sck * gckv[tid + 256];
  if (tid < 32) {
    float a = r[2048 + tid], b = r[2080 + tid];
    orow[512 + tid] = a * cs[t * 64 + tid] - b * sn[t * 64 + tid];
    orow[544 + tid] = b * cs[t * 64 + 32 + tid] + a * sn[t * 64 + 32 + tid];
  }
}

extern "C" void kernel_launch(void* const* d_in, const int* in_sizes, int n_in,
                              void* d_out, int out_size, void* d_ws, size_t ws_size,
                              hipStream_t stream) {
  const float* token_x = (const float*)d_in[0];   // 4096 x 7168
  const float* wq_a = (const float*)d_in[1];      // 7168 x 1536
  const float* wq_b = (const float*)d_in[2];      // 1536 x 24576
  const float* wkv = (const float*)d_in[3];       // 7168 x 576
  const float* rope_cos = (const float*)d_in[4];  // 4096 x 64
  const float* rope_sin = (const float*)d_in[5];
  const float* gamma_cq = (const float*)d_in[6];   // 1536
  const float* gamma_ckv = (const float*)d_in[7];  // 512
  float* out = (float*)d_out;                      // 4096 x 25152

  char* ws = (char*)d_ws;
  unsigned short* txb = (unsigned short*)ws;                          // 4096x7168 bf16
  unsigned short* wqbT = (unsigned short*)(ws + 58720256);            // 24576x1536 bf16
  unsigned short* Bc = (unsigned short*)(ws + 134217728);             // 2176x7168 bf16
  float* raw = (float*)(ws + 165412864);                              // 4096x2176 f32
  unsigned short* cqb = (unsigned short*)(ws + 201064448);            // 4096x1536 bf16

  // 1) conversions
  cvt_bf16<<<28672, 256, 0, stream>>>(token_x, txb);
  transpose_cvt<<<dim3(7168 / 32, 1536 / 32), dim3(32, 8), 0, stream>>>(wq_a, Bc, 7168, 1536, 1536);
  transpose_cvt<<<dim3(7168 / 32, 640 / 32), dim3(32, 8), 0, stream>>>(
      wkv, Bc + (size_t)1536 * 7168, 7168, 576, 640);
  transpose_cvt<<<dim3(1536 / 32, 24576 / 32), dim3(32, 8), 0, stream>>>(wq_b, wqbT, 1536, 24576, 24576);

  // 2) fused GEMM1+GEMM3: raw = token_x @ [wq_a | wkv | 0pad]  (4096 x 2176, K=7168)
  gemm128<<<dim3(17, 32), 256, 0, stream>>>(txb, Bc, raw, 7168, 2176, 2176);

  // 3) merged stage-1 epilogue
  epi1<<<4096, 256, 0, stream>>>(raw, gamma_cq, gamma_ckv, rope_cos, rope_sin, cqb, out);

  // 4) GEMM2 (de-pinned 256^2, fused rope): q = cq @ wq_b -> out cols [0, 24576), K=1536
  //    grid = 16 Mtiles * 96 Ntiles = 1536 (% 8 == 0 for XCD swizzle)
  gemm256<<<1536, 512, 0, stream>>>(cqb, wqbT, out, 1536, OUT_LD, 16, rope_cos, rope_sin, 1);
}

// Round 9
// 682.632 us; speedup vs baseline: 1.2023x; 1.0021x over previous
//
#include <hip/hip_runtime.h>

// MLA projection: T=4096, H=7168, N_HEADS=128, QK_NOPE=128, QK_ROPE=64, KV_RANK=512
// out row = [q (128*192=24576) | ckv (512) | k_rope (64)] = 25152 fp32

typedef __attribute__((ext_vector_type(8))) __bf16 bf16x8;
typedef __attribute__((ext_vector_type(4))) float f32x4;

#define OUT_LD 25152

__device__ __forceinline__ unsigned short f2bf(float f) {
  union { float f; unsigned u; } v; v.f = f;
  unsigned r = v.u + 0x7FFFu + ((v.u >> 16) & 1u);  // RNE
  return (unsigned short)(r >> 16);
}

__device__ __forceinline__ void gload16(const void* g, void* l) {
  __builtin_amdgcn_global_load_lds(
      (__attribute__((address_space(1))) void*)(void*)g,
      (__attribute__((address_space(3))) void*)l, 16, 0, 0);
}

// ---- fp32 -> bf16 straight conversion (token_x), 4 elems/thread ----
__global__ void cvt_bf16(const float* __restrict__ in, unsigned short* __restrict__ out) {
  size_t i = (size_t)blockIdx.x * 256 + threadIdx.x;
  float4 f = ((const float4*)in)[i];
  ushort4 o;
  o.x = f2bf(f.x); o.y = f2bf(f.y); o.z = f2bf(f.z); o.w = f2bf(f.w);
  ((ushort4*)out)[i] = o;
}

// ---- fp32 (K x N) -> bf16 (Npad x K) transpose+convert, zero pad rows >= N ----
__global__ void transpose_cvt(const float* __restrict__ in, unsigned short* __restrict__ out,
                              int K, int N, int Npad) {
  __shared__ float tile[32][33];
  int k0 = blockIdx.x * 32, n0 = blockIdx.y * 32;
  int tx = threadIdx.x, ty = threadIdx.y;  // 32 x 8
#pragma unroll
  for (int i = 0; i < 4; ++i) {
    int k = k0 + ty + i * 8;
    int n = n0 + tx;
    tile[ty + i * 8][tx] = (n < N) ? in[(size_t)k * N + n] : 0.f;
  }
  __syncthreads();
#pragma unroll
  for (int i = 0; i < 4; ++i) {
    int n = n0 + ty + i * 8;
    int k = k0 + tx;
    if (n < Npad) out[(size_t)n * K + k] = f2bf(tile[tx][ty + i * 8]);
  }
}

// ======================================================================
// 256x256 GEMM, round-9: r8 de-pinned base + T19 sched_group_barrier
// interleave. Regime: 1 block/CU, 2 waves/SIMD, no TLP -> compiler's
// read-burst/MFMA-burst emission serializes the LDS and matrix pipes.
// SGB forces {8 VMEM stage | 12 DS (af0+bb0) | 12x{4 MFMA,1 DS} | 16 MFMA}
// per K-tile so bb1/af1 reads drain UNDER the first 48 MFMAs. Deps stay
// compiler-managed (auto lgkmcnt). One __syncthreads() per K-tile.
// T1 XCD swizzle, T2 3-bit XOR swizzle (0 conflicts), T5 setprio.
// A (M,K) k-contig, B (N,K) k-contig, C fp32.
// 512 threads = 8 waves (2 M x 4 N). BK=64. LDS 128 KiB (2 dbuf).
// ======================================================================
__global__ __launch_bounds__(512, 2) void gemm256(
    const unsigned short* __restrict__ A, const unsigned short* __restrict__ B,
    float* __restrict__ C, int K, int ldc, int Mtiles,
    const float* __restrict__ cs, const float* __restrict__ sn, int rope) {
  __shared__ __attribute__((aligned(128))) char lds[131072];
  const int tid = threadIdx.x;
  const int lane = tid & 63;
  const int wr = (tid >> 6) >> 2;  // 0..1
  const int wc = (tid >> 6) & 3;   // 0..3
  const int NT = K >> 6;

  // T1: XCD-aware block swizzle (grid % 8 == 0 by launch)
  const int nwg = gridDim.x;
  const int per = nwg >> 3;
  const int bid = blockIdx.x;
  const int swz = (bid & 7) * per + (bid >> 3);
  const int bm = swz % Mtiles, bn = swz / Mtiles;

  // staging geometry: thread covers 16 B at linear LDS byte tid*16;
  // ldsrow = tid>>3, chunk = tid&7; source col pre-swizzled (rule #21)
  const int strow = tid >> 3;
  const int stcolb = (((tid & 7) ^ ((tid >> 3) & 7)) << 4);
  const size_t abase = (size_t)(bm * 256) * K;
  const size_t bbase = (size_t)(bn * 256) * K;

  f32x4 acc[2][2][4][2];
  const f32x4 z4 = {0.f, 0.f, 0.f, 0.f};
#pragma unroll
  for (int a = 0; a < 2; ++a)
#pragma unroll
    for (int b = 0; b < 2; ++b)
#pragma unroll
      for (int c = 0; c < 4; ++c)
#pragma unroll
        for (int d = 0; d < 2; ++d) acc[a][b][c][d] = z4;

// A LDS: region buf*65536 + 0,     rows 0..255 natural (row = m), 128 B/row
// B LDS: region buf*65536 + 32768, rows permuted: ldsrow(n) = ((n>>5)&1)*128 + ((n>>6)&3)*32 + (n&31)
#define STAGE_A(kt, bsel, u)                                                          \
  do {                                                                                \
    int row_ = (u) * 64 + strow;                                                      \
    gload16((const char*)(A + abase + (size_t)row_ * K + (size_t)(kt) * 64) + stcolb, \
            lds + (bsel) * 65536 + (u) * 8192 + tid * 16);                            \
  } while (0)
#define STAGE_B(kt, bsel, u)                                                          \
  do {                                                                                \
    int lrow_ = (u) * 64 + strow;                                                     \
    int n_ = ((lrow_ >> 5) & 3) * 64 + ((lrow_ >> 7) & 1) * 32 + (lrow_ & 31);        \
    gload16((const char*)(B + bbase + (size_t)n_ * K + (size_t)(kt) * 64) + stcolb,   \
            lds + (bsel) * 65536 + 32768 + (u) * 8192 + tid * 16);                    \
  } while (0)

#define READ_A(dst, QM, LBASE)                                              \
  do {                                                                      \
    _Pragma("unroll") for (int mf = 0; mf < 4; ++mf)                        \
        _Pragma("unroll") for (int ks = 0; ks < 2; ++ks) {                  \
      int row_ = (QM) * 128 + wr * 64 + mf * 16 + (lane & 15);              \
      int in_ = (ks * 64 + ((lane >> 4) << 4)) ^ ((row_ & 7) << 4);         \
      dst[mf][ks] = *(const bf16x8*)((LBASE) + row_ * 128 + in_);           \
    }                                                                       \
  } while (0)
#define READ_B(dst, QN, LBASE)                                              \
  do {                                                                      \
    _Pragma("unroll") for (int nf = 0; nf < 2; ++nf)                        \
        _Pragma("unroll") for (int ks = 0; ks < 2; ++ks) {                  \
      int c_ = wc * 64 + (QN) * 32 + nf * 16 + (lane & 15);                 \
      int rr_ = ((c_ >> 5) & 1) * 128 + ((c_ >> 6) & 3) * 32 + (c_ & 31);   \
      int in_ = (ks * 64 + ((lane >> 4) << 4)) ^ ((rr_ & 7) << 4);          \
      dst[nf][ks] = *(const bf16x8*)((LBASE) + 32768 + rr_ * 128 + in_);    \
    }                                                                       \
  } while (0)
#define MFMA_Q(QM, QN, AF, BB)                                              \
  do {                                                                      \
    _Pragma("unroll") for (int mf = 0; mf < 4; ++mf)                        \
        _Pragma("unroll") for (int nf = 0; nf < 2; ++nf)                    \
            _Pragma("unroll") for (int ks = 0; ks < 2; ++ks)                \
                acc[QM][QN][mf][nf] = __builtin_amdgcn_mfma_f32_16x16x32_bf16( \
                    AF[mf][ks], BB[nf][ks], acc[QM][QN][mf][nf], 0, 0, 0);  \
  } while (0)

  // ---- prologue: stage tile0 -> buf0 ----
  STAGE_A(0, 0, 0); STAGE_A(0, 0, 1); STAGE_A(0, 0, 2); STAGE_A(0, 0, 3);
  STAGE_B(0, 0, 0); STAGE_B(0, 0, 1); STAGE_B(0, 0, 2); STAGE_B(0, 0, 3);
  __syncthreads();  // vmcnt(0) + barrier

  bf16x8 af0[4][2], af1[4][2], bb0[2][2], bb1[2][2];

  for (int t = 0; t < NT; ++t) {
    const int buf = t & 1;
    const int pb = buf ^ 1;
    const char* Lb = lds + buf * 65536;

    // stage ALL of tile t+1 into pb — a full iteration of latency budget
    if (t + 1 < NT) {
      STAGE_A(t + 1, pb, 0); STAGE_A(t + 1, pb, 1);
      STAGE_A(t + 1, pb, 2); STAGE_A(t + 1, pb, 3);
      STAGE_B(t + 1, pb, 0); STAGE_B(t + 1, pb, 1);
      STAGE_B(t + 1, pb, 2); STAGE_B(t + 1, pb, 3);
    }

    // reads in source order: af0+bb0 (12) first, then bb1+af1 (12)
    READ_A(af0, 0, Lb);
    READ_B(bb0, 0, Lb);
    READ_B(bb1, 1, Lb);
    READ_A(af1, 1, Lb);

    __builtin_amdgcn_s_setprio(1);
    MFMA_Q(0, 0, af0, bb0);
    MFMA_Q(0, 1, af0, bb1);
    MFMA_Q(1, 1, af1, bb1);
    MFMA_Q(1, 0, af1, bb0);
    __builtin_amdgcn_s_setprio(0);

    // T19: forced emission order for this scheduling region.
    // masks: VMEM=0x10, DS_READ=0x100, MFMA=0x8
    __builtin_amdgcn_sched_group_barrier(0x10, 8, 0);    // 8 stage loads first
    __builtin_amdgcn_sched_group_barrier(0x100, 12, 0);  // af0+bb0
#pragma unroll
    for (int g = 0; g < 12; ++g) {
      __builtin_amdgcn_sched_group_barrier(0x8, 4, 0);   // 4 MFMA
      __builtin_amdgcn_sched_group_barrier(0x100, 1, 0); // 1 ds_read (bb1/af1)
    }
    __builtin_amdgcn_sched_group_barrier(0x8, 16, 0);    // remaining MFMA

    // boundary: drains vmcnt(0) (t+1 staged) + barrier in one op
    __syncthreads();
  }

  // ---- epilogue: C write, optional fused RoPE on 64-col rope strips ----
  const int colbase = bn * 256 + wc * 64;
  const int rbase = bm * 256 + wr * 64 + ((lane >> 4) << 2);
  const bool isrope = rope && ((colbase % 192) == 128);
  if (isrope) {
#pragma unroll
    for (int qm = 0; qm < 2; ++qm)
#pragma unroll
      for (int mf = 0; mf < 4; ++mf)
#pragma unroll
        for (int nf = 0; nf < 2; ++nf) {
          int i_ = nf * 16 + (lane & 15);
#pragma unroll
          for (int r = 0; r < 4; ++r) {
            int trow = rbase + qm * 128 + mf * 16 + r;
            float c1 = cs[trow * 64 + i_], s1 = sn[trow * 64 + i_];
            float c2 = cs[trow * 64 + 32 + i_], s2 = sn[trow * 64 + 32 + i_];
            float a = acc[qm][0][mf][nf][r], b = acc[qm][1][mf][nf][r];
            C[(size_t)trow * ldc + colbase + i_] = a * c1 - b * s1;
            C[(size_t)trow * ldc + colbase + 32 + i_] = b * c2 + a * s2;
          }
        }
  } else {
#pragma unroll
    for (int qm = 0; qm < 2; ++qm)
#pragma unroll
      for (int qn = 0; qn < 2; ++qn)
#pragma unroll
        for (int mf = 0; mf < 4; ++mf)
#pragma unroll
          for (int nf = 0; nf < 2; ++nf)
#pragma unroll
            for (int r = 0; r < 4; ++r) {
              int trow = rbase + qm * 128 + mf * 16 + r;
              C[(size_t)trow * ldc + colbase + qn * 32 + nf * 16 + (lane & 15)] =
                  acc[qm][qn][mf][nf][r];
            }
  }
#undef MFMA_Q
#undef READ_B
#undef READ_A
#undef STAGE_B
#undef STAGE_A
}

// ---- 128x128 bf16 GEMM (m97 structure) for GEMM1+3: A (M,K), B (N,K), C fp32 ----
__global__ __launch_bounds__(256, 2) void gemm128(
    const unsigned short* __restrict__ A, const unsigned short* __restrict__ B,
    float* __restrict__ C, int K, int ldc, int Nvalid) {
  __shared__ __attribute__((aligned(128))) unsigned short As[128 * 32];
  __shared__ __attribute__((aligned(128))) unsigned short Bs[128 * 32];
  const int tid = threadIdx.x;
  const int lane = tid & 63;
  const int wid = tid >> 6;
  const int wr = wid >> 1, wc = wid & 1;
  const int bm = blockIdx.y, bn = blockIdx.x;
  const size_t abase = (size_t)bm * 128 * K;
  const size_t bbase = (size_t)bn * 128 * K;

  f32x4 acc[4][4];
  const f32x4 zero4 = {0.f, 0.f, 0.f, 0.f};
#pragma unroll
  for (int m = 0; m < 4; ++m)
#pragma unroll
    for (int n = 0; n < 4; ++n) acc[m][n] = zero4;

  const int r0 = tid >> 2;
  const int c0 = (tid & 3) * 8;

  for (int k0 = 0; k0 < K; k0 += 32) {
    gload16(A + abase + (size_t)r0 * K + k0 + c0, As + tid * 8);
    gload16(A + abase + (size_t)(r0 + 64) * K + k0 + c0, As + (256 + tid) * 8);
    gload16(B + bbase + (size_t)r0 * K + k0 + c0, Bs + tid * 8);
    gload16(B + bbase + (size_t)(r0 + 64) * K + k0 + c0, Bs + (256 + tid) * 8);
    __syncthreads();
    bf16x8 af[4], bfr[4];
#pragma unroll
    for (int m = 0; m < 4; ++m)
      af[m] = *(const bf16x8*)(As + (wr * 64 + m * 16 + (lane & 15)) * 32 + (lane >> 4) * 8);
#pragma unroll
    for (int n = 0; n < 4; ++n)
      bfr[n] = *(const bf16x8*)(Bs + (wc * 64 + n * 16 + (lane & 15)) * 32 + (lane >> 4) * 8);
#pragma unroll
    for (int m = 0; m < 4; ++m)
#pragma unroll
      for (int n = 0; n < 4; ++n)
        acc[m][n] = __builtin_amdgcn_mfma_f32_16x16x32_bf16(af[m], bfr[n], acc[m][n], 0, 0, 0);
    __syncthreads();
  }

  const int crow0 = bm * 128 + wr * 64 + ((lane >> 4) << 2);
  const int ccol0 = bn * 128 + wc * 64 + (lane & 15);
#pragma unroll
  for (int m = 0; m < 4; ++m) {
#pragma unroll
    for (int n = 0; n < 4; ++n) {
      int col = ccol0 + n * 16;
      if (col < Nvalid) {
#pragma unroll
        for (int r = 0; r < 4; ++r) {
          int row = crow0 + m * 16 + r;
          C[(size_t)row * ldc + col] = acc[m][n][r];
        }
      }
    }
  }
}

// ---- merged stage-1 epilogue: rmsnorm(cq)->bf16, rmsnorm(ckv)+rope(k_rope)->out ----
__global__ void epi1(const float* __restrict__ raw, const float* __restrict__ gcq,
                     const float* __restrict__ gckv, const float* __restrict__ cs,
                     const float* __restrict__ sn, unsigned short* __restrict__ cqb,
                     float* __restrict__ out) {
  __shared__ float red[4];
  int t = blockIdx.x, tid = threadIdx.x;
  const float* r = raw + (size_t)t * 2176;
  // --- cq rmsnorm (cols 0..1535) ---
  float v[6];
  float ss = 0.f;
#pragma unroll
  for (int i = 0; i < 6; ++i) {
    v[i] = r[tid + i * 256];
    ss += v[i] * v[i];
  }
#pragma unroll
  for (int o = 32; o > 0; o >>= 1) ss += __shfl_xor(ss, o, 64);
  if ((tid & 63) == 0) red[tid >> 6] = ss;
  __syncthreads();
  ss = red[0] + red[1] + red[2] + red[3];
  float sc = rsqrtf(ss * (1.f / 1536.f) + 1e-6f);
#pragma unroll
  for (int i = 0; i < 6; ++i)
    cqb[(size_t)t * 1536 + tid + i * 256] = f2bf(v[i] * sc * gcq[tid + i * 256]);
  // --- kv: rmsnorm cols 1536..2047, rope cols 2048..2111 ---
  float v0 = r[1536 + tid], v1 = r[1792 + tid];
  float s2 = v0 * v0 + v1 * v1;
#pragma unroll
  for (int o = 32; o > 0; o >>= 1) s2 += __shfl_xor(s2, o, 64);
  __syncthreads();  // red[] reuse
  if ((tid & 63) == 0) red[tid >> 6] = s2;
  __syncthreads();
  s2 = red[0] + red[1] + red[2] + red[3];
  float sck = rsqrtf(s2 * (1.f / 512.f) + 1e-6f);
  float* orow = out + (size_t)t * OUT_LD + 24576;
  orow[tid] = v0 * sck * gckv[tid];
  orow[tid + 256] = v1 * sck * gckv[tid + 256];
  if (tid < 32) {
    float a = r[2048 + tid], b = r[2080 + tid];
    orow[512 + tid] = a * cs[t * 64 + tid] - b * sn[t * 64 + tid];
    orow[544 + tid] = b * cs[t * 64 + 32 + tid] + a * sn[t * 64 + 32 + tid];
  }
}

extern "C" void kernel_launch(void* const* d_in, const int* in_sizes, int n_in,
                              void* d_out, int out_size, void* d_ws, size_t ws_size,
                              hipStream_t stream) {
  const float* token_x = (const float*)d_in[0];   // 4096 x 7168
  const float* wq_a = (const float*)d_in[1];      // 7168 x 1536
  const float* wq_b = (const float*)d_in[2];      // 1536 x 24576
  const float* wkv = (const float*)d_in[3];       // 7168 x 576
  const float* rope_cos = (const float*)d_in[4];  // 4096 x 64
  const float* rope_sin = (const float*)d_in[5];
  const float* gamma_cq = (const float*)d_in[6];   // 1536
  const float* gamma_ckv = (const float*)d_in[7];  // 512
  float* out = (float*)d_out;                      // 4096 x 25152

  char* ws = (char*)d_ws;
  unsigned short* txb = (unsigned short*)ws;                          // 4096x7168 bf16
  unsigned short* wqbT = (unsigned short*)(ws + 58720256);            // 24576x1536 bf16
  unsigned short* Bc = (unsigned short*)(ws + 134217728);             // 2176x7168 bf16
  float* raw = (float*)(ws + 165412864);                              // 4096x2176 f32
  unsigned short* cqb = (unsigned short*)(ws + 201064448);            // 4096x1536 bf16

  // 1) conversions
  cvt_bf16<<<28672, 256, 0, stream>>>(token_x, txb);
  transpose_cvt<<<dim3(7168 / 32, 1536 / 32), dim3(32, 8), 0, stream>>>(wq_a, Bc, 7168, 1536, 1536);
  transpose_cvt<<<dim3(7168 / 32, 640 / 32), dim3(32, 8), 0, stream>>>(
      wkv, Bc + (size_t)1536 * 7168, 7168, 576, 640);
  transpose_cvt<<<dim3(1536 / 32, 24576 / 32), dim3(32, 8), 0, stream>>>(wq_b, wqbT, 1536, 24576, 24576);

  // 2) fused GEMM1+GEMM3: raw = token_x @ [wq_a | wkv | 0pad]  (4096 x 2176, K=7168)
  gemm128<<<dim3(17, 32), 256, 0, stream>>>(txb, Bc, raw, 7168, 2176, 2176);

  // 3) merged stage-1 epilogue
  epi1<<<4096, 256, 0, stream>>>(raw, gamma_cq, gamma_ckv, rope_cos, rope_sin, cqb, out);

  // 4) GEMM2 (SGB-interleaved 256^2, fused rope): q = cq @ wq_b -> out cols [0, 24576), K=1536
  //    grid = 16 Mtiles * 96 Ntiles = 1536 (% 8 == 0 for XCD swizzle)
  gemm256<<<1536, 512, 0, stream>>>(cqb, wqbT, out, 1536, OUT_LD, 16, rope_cos, rope_sin, 1);
}